// Round 1
// baseline (870.225 us; speedup 1.0000x reference)
//
#include <hip/hip_runtime.h>
#include <math.h>

// ---------------- problem constants ----------------
#define BB   64
#define NAP  256
#define NUE  128
#define DEG  32
#define EAP  (NAP*DEG)   // 8192
#define EUE  (NUE*DEG)   // 4096
#define D1   64
#define D2   32
#define OUTC 64
#define CH   128         // 2*OUT
#define SS   10

#define TINYF 1.17549435e-38f
#define LOG_HALF (-0.69314718f)

// ---------------- threefry2x32 (JAX partitionable mode) ----------------
// jax.random.key(42) -> key=(0,42). split(4): subkey_i = block(key, (0,i)).
// random_bits(key, i) = y0 ^ y1 of block(key, (0,i)).
constexpr unsigned rotl_c(unsigned v, int s) { return (v << s) | (v >> (32 - s)); }
struct KeyPair { unsigned hi, lo; };
constexpr KeyPair tf_ck(unsigned k0, unsigned k1, unsigned x0, unsigned x1) {
  unsigned ks2 = k0 ^ k1 ^ 0x1BD11BDAu;
  x0 += k0; x1 += k1;
  const int R[20] = {13,15,26,6, 17,29,16,24, 13,15,26,6, 17,29,16,24, 13,15,26,6};
  const unsigned ia[5] = {k1, ks2, k0, k1, ks2};
  const unsigned ib[5] = {ks2, k0, k1, ks2, k0};
  for (int g = 0; g < 5; ++g) {
    for (int j = 0; j < 4; ++j) { x0 += x1; x1 = rotl_c(x1, R[g*4+j]); x1 ^= x0; }
    x0 += ia[g]; x1 += ib[g] + (unsigned)(g + 1);
  }
  return KeyPair{x0, x1};
}
constexpr KeyPair SK1 = tf_ck(0u, 42u, 0u, 0u);  // k1: logistic noise AP
constexpr KeyPair SK2 = tf_ck(0u, 42u, 0u, 1u);  // k2: logistic noise UE
constexpr KeyPair SK3 = tf_ck(0u, 42u, 0u, 2u);  // k3: normal eps AP
constexpr KeyPair SK4 = tf_ck(0u, 42u, 0u, 3u);  // k4: normal eps UE

__device__ __forceinline__ unsigned rb32(unsigned k0, unsigned k1, unsigned ctr) {
  const unsigned ks2 = k0 ^ k1 ^ 0x1BD11BDAu;
  unsigned x0 = k0;          // hi counter word is 0
  unsigned x1 = ctr + k1;
#define TFR(r) { x0 += x1; x1 = (x1 << r) | (x1 >> (32 - r)); x1 ^= x0; }
  TFR(13) TFR(15) TFR(26) TFR(6)
  x0 += k1;  x1 += ks2 + 1u;
  TFR(17) TFR(29) TFR(16) TFR(24)
  x0 += ks2; x1 += k0 + 2u;
  TFR(13) TFR(15) TFR(26) TFR(6)
  x0 += k0;  x1 += k1 + 3u;
  TFR(17) TFR(29) TFR(16) TFR(24)
  x0 += k1;  x1 += ks2 + 4u;
  TFR(13) TFR(15) TFR(26) TFR(6)
  x0 += ks2; x1 += k0 + 5u;
#undef TFR
  return x0 ^ x1;
}

__device__ __forceinline__ float bits_to_unit(unsigned bits) {
  // JAX uniform core: bitcast((bits>>9)|0x3f800000) - 1.0  in [0,1)
  return __uint_as_float((bits >> 9) | 0x3f800000u) - 1.0f;
}

// XLA ErfInv32 (Giles polynomial) — must match XLA's expansion closely
__device__ __forceinline__ float erfinv_f32(float x) {
  float w = -log1pf(-x * x);
  float p;
  if (w < 5.0f) {
    w = w - 2.5f;
    p = 2.81022636e-08f;
    p = fmaf(p, w, 3.43273939e-07f);
    p = fmaf(p, w, -3.5233877e-06f);
    p = fmaf(p, w, -4.39150654e-06f);
    p = fmaf(p, w, 0.00021858087f);
    p = fmaf(p, w, -0.00125372503f);
    p = fmaf(p, w, -0.00417768164f);
    p = fmaf(p, w, 0.246640727f);
    p = fmaf(p, w, 1.50140941f);
  } else {
    w = sqrtf(w) - 3.0f;
    p = -0.000200214257f;
    p = fmaf(p, w, 0.000100950558f);
    p = fmaf(p, w, 0.00134934322f);
    p = fmaf(p, w, -0.00367342844f);
    p = fmaf(p, w, 0.00573950773f);
    p = fmaf(p, w, -0.0076224613f);
    p = fmaf(p, w, 0.00943887047f);
    p = fmaf(p, w, 1.00167406f);
    p = fmaf(p, w, 2.83297682f);
  }
  return p * x;
}

__device__ __forceinline__ float normal_from_bits(unsigned bits) {
  // u ~ uniform(nextafter(-1,0), 1): span rounds to 2.0f in f32
  float f = bits_to_unit(bits);
  const float lo = -0.99999994f;
  float u = fmaxf(lo, fmaf(f, 2.0f, lo));
  return 1.41421354f * erfinv_f32(u);
}

__device__ __forceinline__ float softplus_f(float x) {
  // jnp.logaddexp(x, 0) = max(x,0) + log1p(exp(-|x|))
  return fmaxf(x, 0.0f) + log1pf(expf(-fabsf(x)));
}

// ---------------- kernel 1: edge gate + KL ----------------
__global__ __launch_bounds__(256) void edge_gate_kernel(
    const float* __restrict__ A, const int* __restrict__ Graph,
    const float* __restrict__ Att, float* __restrict__ gate,
    float* __restrict__ IAZ, int N, int E, unsigned k0, unsigned k1)
{
  const int b = blockIdx.y;
  const int e = blockIdx.x * 256 + (int)threadIdx.x;
  const int* G = Graph + (size_t)b * 2 * E;
  const int i_idx = G[E + e];   // Graph[:,1] -> x_i
  const int j_idx = G[e];       // Graph[:,0] -> x_j
  const float* Ab = A + (size_t)b * D1 * N;
  float si = 0.f, sj = 0.f;
  #pragma unroll
  for (int d = 0; d < D1; ++d) {
    si = fmaf(Ab[d * N + i_idx], Att[d], si);
    sj = fmaf(Ab[d * N + j_idx], Att[D1 + d], sj);
  }
  float score = si + sj;
  float l = (score >= 0.f) ? score : 0.2f * score;
  float sig = 1.f / (1.f + expf(-l));
  float a = fminf(fmaxf(sig, 0.01f), 0.99f);
  float logits = logf(a) - log1pf(-a);
  unsigned bits = rb32(k0, k1, (unsigned)(b * E + e));
  float f = bits_to_unit(bits);
  float u = fmaxf(TINYF, f + TINYF);
  float noise = logf(u) - log1pf(-u);
  float gv = 1.f / (1.f + expf(-((logits + noise) / 0.1f)));
  gate[(size_t)b * E + e] = gv;
  float kl = a * (logf(a) - LOG_HALF) + (1.f - a) * (log1pf(-a) - LOG_HALF);
  #pragma unroll
  for (int m = 32; m; m >>= 1) kl += __shfl_xor(kl, m, 64);
  __shared__ float kp[4];
  if ((threadIdx.x & 63) == 0) kp[threadIdx.x >> 6] = kl;
  __syncthreads();
  if (threadIdx.x == 0) atomicAdd(&IAZ[b], kp[0] + kp[1] + kp[2] + kp[3]);
}

// ---------------- kernel 2: degree-32 aggregation + raw column-sum ----------------
template<int N, int E>
__global__ __launch_bounds__(256) void agg_kernel(
    const float* __restrict__ A, const int* __restrict__ Graph,
    const float* __restrict__ gate, const int* __restrict__ GFA,
    float* __restrict__ Aout, float* __restrict__ AmeanRaw)
{
  const int b = blockIdx.y;
  const int wave = threadIdx.x >> 6, lane = threadIdx.x & 63;
  const int n = blockIdx.x * 64 + lane;
  const int* G0 = Graph + (size_t)b * 2 * E;     // row 0 = source nodes
  const float* gb = gate + (size_t)b * E;
  const int* gfa = GFA + ((size_t)b * N + n) * DEG;
  int jj[DEG]; float gg[DEG];
  #pragma unroll
  for (int k = 0; k < DEG; ++k) {
    int e = gfa[k];
    jj[k] = G0[e];
    gg[k] = gb[e];
  }
  const float* Ab = A + (size_t)b * D1 * N;
  for (int dd = 0; dd < 16; ++dd) {
    int d = wave * 16 + dd;
    const float* Ar = Ab + (size_t)d * N;
    float acc = 0.f;
    #pragma unroll
    for (int k = 0; k < DEG; ++k) acc = fmaf(gg[k], Ar[jj[k]], acc);
    Aout[((size_t)b * D1 + d) * N + n] = acc;
    float s = acc;
    #pragma unroll
    for (int m = 32; m; m >>= 1) s += __shfl_xor(s, m, 64);
    if (lane == 0) atomicAdd(&AmeanRaw[b * D1 + d], s);
  }
}

// ---------------- kernel 3: H -> mean over NUE (Hm1) and over NAP (Hm2) ----------------
__global__ __launch_bounds__(256) void hreduce_kernel(
    const float* __restrict__ H, float* __restrict__ Hm1, float* __restrict__ Hm2)
{
  const int bd = blockIdx.x;                         // b*D2 + d2
  const float* Hp = H + (size_t)bd * NAP * NUE;
  const int t = threadIdx.x;
  const int tx = t & 31, ty = t >> 5;                // tx: NUE/4 group, ty: row phase
  float4 col = {0.f, 0.f, 0.f, 0.f};
  for (int i = ty; i < NAP; i += 8) {
    float4 v = ((const float4*)(Hp + (size_t)i * NUE))[tx];
    col.x += v.x; col.y += v.y; col.z += v.z; col.w += v.w;
    float rs = v.x + v.y + v.z + v.w;
    #pragma unroll
    for (int m = 16; m; m >>= 1) rs += __shfl_xor(rs, m, 64);  // sums within 32-lane halves
    if (tx == 0) Hm1[(size_t)bd * NAP + i] = rs * (1.0f / NUE);
  }
  __shared__ float cp[8 * 128];
  ((float4*)cp)[ty * 32 + tx] = col;
  __syncthreads();
  if (t < 128) {
    float s = 0.f;
    #pragma unroll
    for (int r = 0; r < 8; ++r) s += cp[r * 128 + t];
    Hm2[(size_t)bd * NUE + t] = s * (1.0f / NAP);
  }
}

// ---------------- kernel 4: broadcast Q2 term ----------------
__global__ __launch_bounds__(128) void qterm_kernel(
    const float* __restrict__ Q2_AP, const float* __restrict__ Q2_UE,
    const float* __restrict__ AapMeanRaw, const float* __restrict__ AueMeanRaw,
    float* __restrict__ qbAP, float* __restrict__ qbUE)
{
  const int b = blockIdx.x;
  const int o = threadIdx.x;   // 0..127
  float sA = 0.f, sU = 0.f;
  #pragma unroll
  for (int d = 0; d < D1; ++d) {
    float mUE = AueMeanRaw[b * D1 + d] * (1.0f / NUE);
    float mAP = AapMeanRaw[b * D1 + d] * (1.0f / NAP);
    sA = fmaf(Q2_AP[o * D1 + d], mUE, sA);
    sU = fmaf(Q2_UE[o * D1 + d], mAP, sU);
  }
  qbAP[b * CH + o] = 2.f * sA;
  qbUE[b * CH + o] = 2.f * sU;
}

// ---------------- kernel 5: einsums + relu + BN partial stats ----------------
__global__ __launch_bounds__(256) void mix_kernel(
    const float* __restrict__ Aagg, const float* __restrict__ Hm,
    const float* __restrict__ Q1, const float* __restrict__ P1,
    const float* __restrict__ qb, float* __restrict__ pre,
    float* __restrict__ stat, int N)
{
  const int b = blockIdx.z;
  const int ntile = blockIdx.x;       // tiles of 128 n
  const int obase = blockIdx.y * 8;   // 16 y-blocks * 8 o
  __shared__ float As2[D1 * 128];
  __shared__ float Hs[D2 * 128];
  const int t = threadIdx.x;
  const float* Ab = Aagg + (size_t)b * D1 * N + ntile * 128;
  for (int idx = t; idx < D1 * 128; idx += 256) {
    int d = idx >> 7, n = idx & 127;
    As2[idx] = Ab[(size_t)d * N + n];
  }
  const float* Hb = Hm + (size_t)b * D2 * N + ntile * 128;
  for (int idx = t; idx < D2 * 128; idx += 256) {
    int c = idx >> 7, n = idx & 127;
    Hs[idx] = Hb[(size_t)c * N + n];
  }
  __syncthreads();
  const int half = t >> 7, n = t & 127;
  #pragma unroll
  for (int oi = 0; oi < 4; ++oi) {
    const int o = obase + half * 4 + oi;
    float acc = 0.f;
    #pragma unroll
    for (int d = 0; d < D1; ++d) acc = fmaf(Q1[o * D1 + d], As2[d * 128 + n], acc);
    float acc2 = 0.f;
    #pragma unroll
    for (int c = 0; c < D2; ++c) acc2 = fmaf(P1[o * D2 + c], Hs[c * 128 + n], acc2);
    float r = 2.f * acc + qb[b * CH + o] + 0.1f * acc2;
    r = fmaxf(r, 0.f);
    pre[((size_t)b * CH + o) * N + ntile * 128 + n] = r;
    float s1 = r, s2 = r * r;
    #pragma unroll
    for (int m = 32; m; m >>= 1) { s1 += __shfl_xor(s1, m, 64); s2 += __shfl_xor(s2, m, 64); }
    if ((t & 63) == 0) { atomicAdd(&stat[o], s1); atomicAdd(&stat[CH + o], s2); }
  }
}

// ---------------- kernel 6: BN scale/shift ----------------
__global__ __launch_bounds__(256) void bnfinal_kernel(
    const float* __restrict__ statAP, const float* __restrict__ statUE,
    const float* __restrict__ bnw, const float* __restrict__ bnb,
    float* __restrict__ ssAP, float* __restrict__ ssUE)
{
  const int t = threadIdx.x;
  if (t < CH) {
    const float inv = 1.0f / (BB * NAP);
    float m = statAP[t] * inv;
    float v = statAP[CH + t] * inv - m * m;
    float sc = bnw[t] / sqrtf(v + 1e-5f);
    ssAP[t] = sc; ssAP[CH + t] = bnb[t] - m * sc;
  } else {
    const int o = t - CH;
    const float inv = 1.0f / (BB * NUE);
    float m = statUE[o] * inv;
    float v = statUE[CH + o] * inv - m * m;
    float sc = bnw[o] / sqrtf(v + 1e-5f);
    ssUE[o] = sc; ssUE[CH + o] = bnb[o] - m * sc;
  }
}

// ---------------- kernel 7: normalize + write outputs + info_xz ----------------
__global__ __launch_bounds__(256) void finalize_kernel(
    const float* __restrict__ preAP, const float* __restrict__ preUE,
    const float* __restrict__ ssAP, const float* __restrict__ ssUE,
    float* __restrict__ outAP, float* __restrict__ outUE,
    float* __restrict__ IXZAP, float* __restrict__ IXZUE)
{
  const int side = blockIdx.z;          // 0 = AP, 1 = UE
  const int N = side ? NUE : NAP;
  if ((int)blockIdx.x * 64 >= N) return;
  const float* pre = side ? preUE : preAP;
  const float* ss  = side ? ssUE  : ssAP;
  float* outp      = side ? outUE : outAP;
  float* IXZ       = side ? IXZUE : IXZAP;
  const unsigned k0 = side ? SK4.hi : SK3.hi;
  const unsigned k1 = side ? SK4.lo : SK3.lo;
  const int ROWS = BB * N;

  const int b = blockIdx.y;
  const int lane = threadIdx.x & 63;
  const int og = threadIdx.x >> 6;      // 0..3, o-range [og*16, og*16+16)
  const int n = blockIdx.x * 64 + lane;
  const int row = b * N + n;
  const float* preb = pre + (size_t)b * CH * N;

  float accZ = 0.f, sumlog = 0.f;
  for (int oi = 0; oi < 16; ++oi) {
    const int o = og * 16 + oi;
    float mpre = preb[o * N + n];
    float rraw = preb[(o + 64) * N + n];
    float x0 = fmaf(mpre, ss[o], ss[CH + o]);             // normalized mean channel
    float x1 = fmaf(rraw, ss[o + 64], ss[CH + o + 64]);   // normalized raw channel
    outp[((size_t)b * OUTC + o) * N + n] = x0;
    float stdv = softplus_f(x1) + 1e-10f;
    float lstd = logf(stdv);
    sumlog += lstd;
    #pragma unroll
    for (int s = 0; s < SS; ++s) {
      unsigned idx = (unsigned)((s * ROWS + row) * 64 + o);
      float eps = normal_from_bits(rb32(k0, k1, idx));
      float Z = fmaf(stdv, eps, x0);
      accZ += 0.5f * (Z * Z - eps * eps);
    }
  }
  __shared__ float pz[4][64];
  __shared__ float pl[4][64];
  pz[og][lane] = accZ; pl[og][lane] = sumlog;
  __syncthreads();
  if (og == 0) {
    float az = pz[0][lane] + pz[1][lane] + pz[2][lane] + pz[3][lane];
    float al = pl[0][lane] + pl[1][lane] + pl[2][lane] + pl[3][lane];
    float rv = az * (1.0f / SS) - al;   // per-row (logq-logp).mean(0)
    #pragma unroll
    for (int m = 32; m; m >>= 1) rv += __shfl_xor(rv, m, 64);
    if (lane == 0) atomicAdd(&IXZ[b], rv);
  }
}

// ---------------- workspace layout (floats) ----------------
constexpr size_t OFF_AMEAN_AP = 0;                                   // zeroed
constexpr size_t OFF_AMEAN_UE = OFF_AMEAN_AP + BB * D1;              // zeroed
constexpr size_t OFF_STAT_AP  = OFF_AMEAN_UE + BB * D1;              // zeroed
constexpr size_t OFF_STAT_UE  = OFF_STAT_AP + 2 * CH;                // zeroed
constexpr size_t OFF_GATE_AP  = OFF_STAT_UE + 2 * CH;
constexpr size_t OFF_GATE_UE  = OFF_GATE_AP + (size_t)BB * EAP;
constexpr size_t OFF_AAP      = OFF_GATE_UE + (size_t)BB * EUE;
constexpr size_t OFF_AUE      = OFF_AAP + (size_t)BB * D1 * NAP;
constexpr size_t OFF_HM1      = OFF_AUE + (size_t)BB * D1 * NUE;
constexpr size_t OFF_HM2      = OFF_HM1 + (size_t)BB * D2 * NAP;
constexpr size_t OFF_PRE_AP   = OFF_HM2 + (size_t)BB * D2 * NUE;
constexpr size_t OFF_PRE_UE   = OFF_PRE_AP + (size_t)BB * CH * NAP;
constexpr size_t OFF_QB_AP    = OFF_PRE_UE + (size_t)BB * CH * NUE;
constexpr size_t OFF_QB_UE    = OFF_QB_AP + BB * CH;
constexpr size_t OFF_SS_AP    = OFF_QB_UE + BB * CH;
constexpr size_t OFF_SS_UE    = OFF_SS_AP + 2 * CH;
constexpr size_t WS_FLOATS    = OFF_SS_UE + 2 * CH;

extern "C" void kernel_launch(void* const* d_in, const int* in_sizes, int n_in,
                              void* d_out, int out_size, void* d_ws, size_t ws_size,
                              hipStream_t stream)
{
  const float* A_AP  = (const float*)d_in[0];
  const float* A_UE  = (const float*)d_in[1];
  const float* H     = (const float*)d_in[2];
  const float* Q1_AP = (const float*)d_in[3];
  const float* Q2_AP = (const float*)d_in[4];
  const float* Q1_UE = (const float*)d_in[5];
  const float* Q2_UE = (const float*)d_in[6];
  const float* P1_AP = (const float*)d_in[7];
  const float* P1_UE = (const float*)d_in[8];
  const float* AttAP = (const float*)d_in[9];
  const float* AttUE = (const float*)d_in[10];
  const float* bnw   = (const float*)d_in[11];
  const float* bnb   = (const float*)d_in[12];
  const int* GraphAP = (const int*)d_in[13];
  const int* GraphUE = (const int*)d_in[14];
  const int* GFA_AP  = (const int*)d_in[15];
  const int* GFA_UE  = (const int*)d_in[16];

  float* ws = (float*)d_ws;
  if (ws_size < WS_FLOATS * sizeof(float)) return;  // insufficient scratch

  float* amAP  = ws + OFF_AMEAN_AP;
  float* amUE  = ws + OFF_AMEAN_UE;
  float* stAP  = ws + OFF_STAT_AP;
  float* stUE  = ws + OFF_STAT_UE;
  float* gAP   = ws + OFF_GATE_AP;
  float* gUE   = ws + OFF_GATE_UE;
  float* Aap   = ws + OFF_AAP;
  float* Aue   = ws + OFF_AUE;
  float* Hm1   = ws + OFF_HM1;
  float* Hm2   = ws + OFF_HM2;
  float* preAP = ws + OFF_PRE_AP;
  float* preUE = ws + OFF_PRE_UE;
  float* qbAP  = ws + OFF_QB_AP;
  float* qbUE  = ws + OFF_QB_UE;
  float* ssAP  = ws + OFF_SS_AP;
  float* ssUE  = ws + OFF_SS_UE;

  float* out     = (float*)d_out;
  float* outAP   = out;                                  // (B, OUT, NAP)
  float* outUE   = out + (size_t)BB * OUTC * NAP;        // (B, OUT, NUE)
  float* IXZ_AP  = out + (size_t)BB * OUTC * (NAP + NUE);
  float* IXZ_UE  = IXZ_AP + BB;
  float* IAZ_AP  = IXZ_UE + BB;
  float* IAZ_UE  = IAZ_AP + BB;

  // zero accumulators (ws is poisoned 0xAA each call; out tail holds atomics)
  hipMemsetAsync(ws, 0, (OFF_GATE_AP) * sizeof(float), stream);
  hipMemsetAsync(IXZ_AP, 0, 4 * BB * sizeof(float), stream);

  // 1) edge gates + KL
  edge_gate_kernel<<<dim3(EAP / 256, BB), 256, 0, stream>>>(
      A_AP, GraphAP, AttAP, gAP, IAZ_AP, NAP, EAP, SK1.hi, SK1.lo);
  edge_gate_kernel<<<dim3(EUE / 256, BB), 256, 0, stream>>>(
      A_UE, GraphUE, AttUE, gUE, IAZ_UE, NUE, EUE, SK2.hi, SK2.lo);

  // 2) H means (dominant HBM traffic: 256 MB)
  hreduce_kernel<<<BB * D2, 256, 0, stream>>>(H, Hm1, Hm2);

  // 3) aggregation
  agg_kernel<NAP, EAP><<<dim3(NAP / 64, BB), 256, 0, stream>>>(
      A_AP, GraphAP, gAP, GFA_AP, Aap, amAP);
  agg_kernel<NUE, EUE><<<dim3(NUE / 64, BB), 256, 0, stream>>>(
      A_UE, GraphUE, gUE, GFA_UE, Aue, amUE);

  // 4) Q2 broadcast terms
  qterm_kernel<<<BB, 128, 0, stream>>>(Q2_AP, Q2_UE, amAP, amUE, qbAP, qbUE);

  // 5) einsums + relu + BN stats
  mix_kernel<<<dim3(NAP / 128, 16, BB), 256, 0, stream>>>(
      Aap, Hm1, Q1_AP, P1_AP, qbAP, preAP, stAP, NAP);
  mix_kernel<<<dim3(NUE / 128, 16, BB), 256, 0, stream>>>(
      Aue, Hm2, Q1_UE, P1_UE, qbUE, preUE, stUE, NUE);

  // 6) BN scale/shift
  bnfinal_kernel<<<1, 256, 0, stream>>>(stAP, stUE, bnw, bnb, ssAP, ssUE);

  // 7) normalize + outputs + info_xz (AP and UE concurrently via z)
  finalize_kernel<<<dim3(NAP / 64, BB, 2), 256, 0, stream>>>(
      preAP, preUE, ssAP, ssUE, outAP, outUE, IXZ_AP, IXZ_UE);
}

// Round 2
// 778.483 us; speedup vs baseline: 1.1178x; 1.1178x over previous
//
#include <hip/hip_runtime.h>
#include <math.h>

// ---------------- problem constants ----------------
#define BB   64
#define NAP  256
#define NUE  128
#define DEG  32
#define EAP  (NAP*DEG)   // 8192
#define EUE  (NUE*DEG)   // 4096
#define D1   64
#define D2   32
#define OUTC 64
#define CH   128         // 2*OUT
#define SS   10

#define TINYF 1.17549435e-38f
#define LOG_HALF (-0.69314718f)

// ---------------- threefry2x32 (JAX partitionable mode) ----------------
constexpr unsigned rotl_c(unsigned v, int s) { return (v << s) | (v >> (32 - s)); }
struct KeyPair { unsigned hi, lo; };
constexpr KeyPair tf_ck(unsigned k0, unsigned k1, unsigned x0, unsigned x1) {
  unsigned ks2 = k0 ^ k1 ^ 0x1BD11BDAu;
  x0 += k0; x1 += k1;
  const int R[20] = {13,15,26,6, 17,29,16,24, 13,15,26,6, 17,29,16,24, 13,15,26,6};
  const unsigned ia[5] = {k1, ks2, k0, k1, ks2};
  const unsigned ib[5] = {ks2, k0, k1, ks2, k0};
  for (int g = 0; g < 5; ++g) {
    for (int j = 0; j < 4; ++j) { x0 += x1; x1 = rotl_c(x1, R[g*4+j]); x1 ^= x0; }
    x0 += ia[g]; x1 += ib[g] + (unsigned)(g + 1);
  }
  return KeyPair{x0, x1};
}
constexpr KeyPair SK1 = tf_ck(0u, 42u, 0u, 0u);  // logistic noise AP
constexpr KeyPair SK2 = tf_ck(0u, 42u, 0u, 1u);  // logistic noise UE
constexpr KeyPair SK3 = tf_ck(0u, 42u, 0u, 2u);  // normal eps AP
constexpr KeyPair SK4 = tf_ck(0u, 42u, 0u, 3u);  // normal eps UE

__device__ __forceinline__ unsigned rb32(unsigned k0, unsigned k1, unsigned ctr) {
  const unsigned ks2 = k0 ^ k1 ^ 0x1BD11BDAu;
  unsigned x0 = k0;
  unsigned x1 = ctr + k1;
#define TFR(r) { x0 += x1; x1 = (x1 << r) | (x1 >> (32 - r)); x1 ^= x0; }
  TFR(13) TFR(15) TFR(26) TFR(6)
  x0 += k1;  x1 += ks2 + 1u;
  TFR(17) TFR(29) TFR(16) TFR(24)
  x0 += ks2; x1 += k0 + 2u;
  TFR(13) TFR(15) TFR(26) TFR(6)
  x0 += k0;  x1 += k1 + 3u;
  TFR(17) TFR(29) TFR(16) TFR(24)
  x0 += k1;  x1 += ks2 + 4u;
  TFR(13) TFR(15) TFR(26) TFR(6)
  x0 += ks2; x1 += k0 + 5u;
#undef TFR
  return x0 ^ x1;
}

__device__ __forceinline__ float bits_to_unit(unsigned bits) {
  return __uint_as_float((bits >> 9) | 0x3f800000u) - 1.0f;
}

// XLA ErfInv32 (Giles polynomial)
__device__ __forceinline__ float erfinv_f32(float x) {
  float w = -log1pf(-x * x);
  float p;
  if (w < 5.0f) {
    w = w - 2.5f;
    p = 2.81022636e-08f;
    p = fmaf(p, w, 3.43273939e-07f);
    p = fmaf(p, w, -3.5233877e-06f);
    p = fmaf(p, w, -4.39150654e-06f);
    p = fmaf(p, w, 0.00021858087f);
    p = fmaf(p, w, -0.00125372503f);
    p = fmaf(p, w, -0.00417768164f);
    p = fmaf(p, w, 0.246640727f);
    p = fmaf(p, w, 1.50140941f);
  } else {
    w = sqrtf(w) - 3.0f;
    p = -0.000200214257f;
    p = fmaf(p, w, 0.000100950558f);
    p = fmaf(p, w, 0.00134934322f);
    p = fmaf(p, w, -0.00367342844f);
    p = fmaf(p, w, 0.00573950773f);
    p = fmaf(p, w, -0.0076224613f);
    p = fmaf(p, w, 0.00943887047f);
    p = fmaf(p, w, 1.00167406f);
    p = fmaf(p, w, 2.83297682f);
  }
  return p * x;
}

__device__ __forceinline__ float normal_from_bits(unsigned bits) {
  float f = bits_to_unit(bits);
  const float lo = -0.99999994f;
  float u = fmaxf(lo, fmaf(f, 2.0f, lo));
  return 1.41421354f * erfinv_f32(u);
}

__device__ __forceinline__ float softplus_f(float x) {
  return fmaxf(x, 0.0f) + log1pf(expf(-fabsf(x)));
}

// ---------------- kernel 1: per-node scores -> edge gate + KL (one block per (b,side)) ----------------
// score(e) = dot(A[:,i], att[0:64]) + dot(A[:,j], att[64:128]) is separable:
// precompute si[n], sj[n] once per node (coalesced), then 2 LDS lookups per edge.
__global__ __launch_bounds__(256) void edge_kernel(
    const float* __restrict__ A_AP, const float* __restrict__ A_UE,
    const int* __restrict__ GAP, const int* __restrict__ GUE,
    const float* __restrict__ AttAP, const float* __restrict__ AttUE,
    float* __restrict__ gAP, float* __restrict__ gUE,
    float* __restrict__ IAZ_AP, float* __restrict__ IAZ_UE,
    float* __restrict__ amAP, float* __restrict__ amUE)
{
  const int side = blockIdx.y;
  const int b = blockIdx.x;
  const int N = side ? NUE : NAP;
  const int E = side ? EUE : EAP;
  const float* A  = (side ? A_UE : A_AP) + (size_t)b * D1 * N;
  const int* G    = (side ? GUE : GAP) + (size_t)b * 2 * E;
  const float* At = side ? AttUE : AttAP;
  float* gate     = (side ? gUE : gAP) + (size_t)b * E;
  float* IAZ      = side ? IAZ_UE : IAZ_AP;
  float* am       = side ? amUE : amAP;
  const unsigned k0 = side ? SK2.hi : SK1.hi;
  const unsigned k1 = side ? SK2.lo : SK1.lo;
  const int t = threadIdx.x;

  if (t < D1) am[b * D1 + t] = 0.f;   // zero amean accumulator for agg

  __shared__ float si_s[NAP];
  __shared__ float sj_s[NAP];
  if (t < N) {
    float a0 = 0.f, a1 = 0.f;
    #pragma unroll
    for (int d = 0; d < D1; ++d) {
      float v = A[d * N + t];
      a0 = fmaf(v, At[d], a0);        // same fmaf chain order as reference path
      a1 = fmaf(v, At[D1 + d], a1);
    }
    si_s[t] = a0; sj_s[t] = a1;
  }
  __syncthreads();

  float klacc = 0.f;
  for (int e = t; e < E; e += 256) {
    const int ii = G[E + e];   // Graph[:,1] -> x_i
    const int jj = G[e];       // Graph[:,0] -> x_j
    float score = si_s[ii] + sj_s[jj];
    float l = (score >= 0.f) ? score : 0.2f * score;
    float sig = 1.f / (1.f + expf(-l));
    float a = fminf(fmaxf(sig, 0.01f), 0.99f);
    float logits = logf(a) - log1pf(-a);
    unsigned bits = rb32(k0, k1, (unsigned)(b * E + e));
    float f = bits_to_unit(bits);
    float u = fmaxf(TINYF, f + TINYF);
    float noise = logf(u) - log1pf(-u);
    float gv = 1.f / (1.f + expf(-((logits + noise) / 0.1f)));
    gate[e] = gv;
    klacc += a * (logf(a) - LOG_HALF) + (1.f - a) * (log1pf(-a) - LOG_HALF);
  }
  #pragma unroll
  for (int m = 32; m; m >>= 1) klacc += __shfl_xor(klacc, m, 64);
  __shared__ float red[4];
  if ((t & 63) == 0) red[t >> 6] = klacc;
  __syncthreads();
  if (t == 0) IAZ[b] = red[0] + red[1] + red[2] + red[3];  // direct store, no atomic
}

// ---------------- kernel 2: degree-32 aggregation, gathers from LDS ----------------
template<int N, int E>
__global__ __launch_bounds__(256) void agg_kernel(
    const float* __restrict__ A, const int* __restrict__ Graph,
    const float* __restrict__ gate, const int* __restrict__ GFA,
    float* __restrict__ Aout, float* __restrict__ AmeanRaw)
{
  __shared__ float Als[D1 * N];     // 64 KB (AP) / 32 KB (UE)
  const int b = blockIdx.y;
  const int t = threadIdx.x;
  const int wave = t >> 6, lane = t & 63;
  const int n = blockIdx.x * 64 + lane;

  // per-node edge list gather (global; gate[b]/G0[b] fit in L1)
  const int* G0 = Graph + (size_t)b * 2 * E;
  const float* gb = gate + (size_t)b * E;
  const int* gfa = GFA + ((size_t)b * N + n) * DEG;
  int jj[DEG]; float gg[DEG];
  #pragma unroll
  for (int k = 0; k < DEG; ++k) {
    int e = gfa[k];
    jj[k] = G0[e];
    gg[k] = gb[e];
  }

  // stage A[b] into LDS (coalesced float4)
  const float* Ab = A + (size_t)b * D1 * N;
  for (int idx = t * 4; idx < D1 * N; idx += 1024)
    *(float4*)(Als + idx) = *(const float4*)(Ab + idx);
  __syncthreads();

  for (int dd = 0; dd < 16; ++dd) {
    const int d = wave * 16 + dd;
    const float* Ar = Als + d * N;
    float acc = 0.f;
    #pragma unroll
    for (int k = 0; k < DEG; ++k) acc = fmaf(gg[k], Ar[jj[k]], acc);
    Aout[((size_t)b * D1 + d) * N + n] = acc;
    float s = acc;
    #pragma unroll
    for (int m = 32; m; m >>= 1) s += __shfl_xor(s, m, 64);
    if (lane == 0) atomicAdd(&AmeanRaw[b * D1 + d], s);
  }
}

// ---------------- kernel 3: H -> mean over NUE (Hm1) and over NAP (Hm2) ----------------
__global__ __launch_bounds__(256) void hreduce_kernel(
    const float* __restrict__ H, float* __restrict__ Hm1, float* __restrict__ Hm2)
{
  const int bd = blockIdx.x;                         // b*D2 + d2
  const float* Hp = H + (size_t)bd * NAP * NUE;
  const int t = threadIdx.x;
  const int tx = t & 31, ty = t >> 5;
  float4 col = {0.f, 0.f, 0.f, 0.f};
  for (int i = ty; i < NAP; i += 8) {
    float4 v = ((const float4*)(Hp + (size_t)i * NUE))[tx];
    col.x += v.x; col.y += v.y; col.z += v.z; col.w += v.w;
    float rs = v.x + v.y + v.z + v.w;
    #pragma unroll
    for (int m = 16; m; m >>= 1) rs += __shfl_xor(rs, m, 64);
    if (tx == 0) Hm1[(size_t)bd * NAP + i] = rs * (1.0f / NUE);
  }
  __shared__ float cp[8 * 128];
  ((float4*)cp)[ty * 32 + tx] = col;
  __syncthreads();
  if (t < 128) {
    float s = 0.f;
    #pragma unroll
    for (int r = 0; r < 8; ++r) s += cp[r * 128 + t];
    Hm2[(size_t)bd * NUE + t] = s * (1.0f / NAP);
  }
}

// ---------------- kernel 4: broadcast Q2 term (+ zero BN stats) ----------------
__global__ __launch_bounds__(128) void qterm_kernel(
    const float* __restrict__ Q2_AP, const float* __restrict__ Q2_UE,
    const float* __restrict__ AapMeanRaw, const float* __restrict__ AueMeanRaw,
    float* __restrict__ qbAP, float* __restrict__ qbUE,
    float* __restrict__ stAP, float* __restrict__ stUE)
{
  const int b = blockIdx.x;
  const int o = threadIdx.x;
  if (b == 0) {
    #pragma unroll
    for (int i = o; i < 2 * CH; i += 128) { stAP[i] = 0.f; stUE[i] = 0.f; }
  }
  float sA = 0.f, sU = 0.f;
  #pragma unroll
  for (int d = 0; d < D1; ++d) {
    float mUE = AueMeanRaw[b * D1 + d] * (1.0f / NUE);
    float mAP = AapMeanRaw[b * D1 + d] * (1.0f / NAP);
    sA = fmaf(Q2_AP[o * D1 + d], mUE, sA);
    sU = fmaf(Q2_UE[o * D1 + d], mAP, sU);
  }
  qbAP[b * CH + o] = 2.f * sA;
  qbUE[b * CH + o] = 2.f * sU;
}

// ---------------- kernel 5: einsums + relu + BN partial stats ----------------
__global__ __launch_bounds__(256) void mix_kernel(
    const float* __restrict__ Aagg, const float* __restrict__ Hm,
    const float* __restrict__ Q1, const float* __restrict__ P1,
    const float* __restrict__ qb, float* __restrict__ pre,
    float* __restrict__ stat, int N)
{
  const int b = blockIdx.z;
  const int ntile = blockIdx.x;
  const int obase = blockIdx.y * 8;
  __shared__ float As2[D1 * 128];
  __shared__ float Hs[D2 * 128];
  const int t = threadIdx.x;
  const float* Ab = Aagg + (size_t)b * D1 * N + ntile * 128;
  for (int idx = t; idx < D1 * 128; idx += 256) {
    int d = idx >> 7, n = idx & 127;
    As2[idx] = Ab[(size_t)d * N + n];
  }
  const float* Hb = Hm + (size_t)b * D2 * N + ntile * 128;
  for (int idx = t; idx < D2 * 128; idx += 256) {
    int c = idx >> 7, n = idx & 127;
    Hs[idx] = Hb[(size_t)c * N + n];
  }
  __syncthreads();
  const int half = t >> 7, n = t & 127;
  #pragma unroll
  for (int oi = 0; oi < 4; ++oi) {
    const int o = obase + half * 4 + oi;
    float acc = 0.f;
    #pragma unroll
    for (int d = 0; d < D1; ++d) acc = fmaf(Q1[o * D1 + d], As2[d * 128 + n], acc);
    float acc2 = 0.f;
    #pragma unroll
    for (int c = 0; c < D2; ++c) acc2 = fmaf(P1[o * D2 + c], Hs[c * 128 + n], acc2);
    float r = 2.f * acc + qb[b * CH + o] + 0.1f * acc2;
    r = fmaxf(r, 0.f);
    pre[((size_t)b * CH + o) * N + ntile * 128 + n] = r;
    float s1 = r, s2 = r * r;
    #pragma unroll
    for (int m = 32; m; m >>= 1) { s1 += __shfl_xor(s1, m, 64); s2 += __shfl_xor(s2, m, 64); }
    if ((t & 63) == 0) { atomicAdd(&stat[o], s1); atomicAdd(&stat[CH + o], s2); }
  }
}

// ---------------- kernel 6: BN scale/shift (+ zero IXZ accumulators) ----------------
__global__ __launch_bounds__(256) void bnfinal_kernel(
    const float* __restrict__ statAP, const float* __restrict__ statUE,
    const float* __restrict__ bnw, const float* __restrict__ bnb,
    float* __restrict__ ssAP, float* __restrict__ ssUE,
    float* __restrict__ IXZ)
{
  const int t = threadIdx.x;
  if (t < 2 * BB) IXZ[t] = 0.f;     // IXZ_AP(64) + IXZ_UE(64), contiguous
  if (t < CH) {
    const float inv = 1.0f / (BB * NAP);
    float m = statAP[t] * inv;
    float v = statAP[CH + t] * inv - m * m;
    float sc = bnw[t] / sqrtf(v + 1e-5f);
    ssAP[t] = sc; ssAP[CH + t] = bnb[t] - m * sc;
  } else {
    const int o = t - CH;
    const float inv = 1.0f / (BB * NUE);
    float m = statUE[o] * inv;
    float v = statUE[CH + o] * inv - m * m;
    float sc = bnw[o] / sqrtf(v + 1e-5f);
    ssUE[o] = sc; ssUE[CH + o] = bnb[o] - m * sc;
  }
}

// ---------------- kernel 7: normalize + outputs + info_xz ----------------
__global__ __launch_bounds__(256) void finalize_kernel(
    const float* __restrict__ preAP, const float* __restrict__ preUE,
    const float* __restrict__ ssAP, const float* __restrict__ ssUE,
    float* __restrict__ outAP, float* __restrict__ outUE,
    float* __restrict__ IXZAP, float* __restrict__ IXZUE)
{
  const int side = blockIdx.z;
  const int N = side ? NUE : NAP;
  if ((int)blockIdx.x * 64 >= N) return;
  const float* pre = side ? preUE : preAP;
  const float* ss  = side ? ssUE  : ssAP;
  float* outp      = side ? outUE : outAP;
  float* IXZ       = side ? IXZUE : IXZAP;
  const unsigned k0 = side ? SK4.hi : SK3.hi;
  const unsigned k1 = side ? SK4.lo : SK3.lo;
  const int ROWS = BB * N;

  const int b = blockIdx.y;
  const int lane = threadIdx.x & 63;
  const int og = threadIdx.x >> 6;
  const int n = blockIdx.x * 64 + lane;
  const int row = b * N + n;
  const float* preb = pre + (size_t)b * CH * N;

  float accZ = 0.f, sumlog = 0.f;
  for (int oi = 0; oi < 16; ++oi) {
    const int o = og * 16 + oi;
    float mpre = preb[o * N + n];
    float rraw = preb[(o + 64) * N + n];
    float x0 = fmaf(mpre, ss[o], ss[CH + o]);
    float x1 = fmaf(rraw, ss[o + 64], ss[CH + o + 64]);
    outp[((size_t)b * OUTC + o) * N + n] = x0;
    float stdv = softplus_f(x1) + 1e-10f;
    sumlog += logf(stdv);
    #pragma unroll
    for (int s = 0; s < SS; ++s) {
      unsigned idx = (unsigned)((s * ROWS + row) * 64 + o);
      float eps = normal_from_bits(rb32(k0, k1, idx));
      float Z = fmaf(stdv, eps, x0);
      accZ += 0.5f * (Z * Z - eps * eps);
    }
  }
  __shared__ float pz[4][64];
  __shared__ float pl[4][64];
  pz[og][lane] = accZ; pl[og][lane] = sumlog;
  __syncthreads();
  if (og == 0) {
    float az = pz[0][lane] + pz[1][lane] + pz[2][lane] + pz[3][lane];
    float al = pl[0][lane] + pl[1][lane] + pl[2][lane] + pl[3][lane];
    float rv = az * (1.0f / SS) - al;
    #pragma unroll
    for (int m = 32; m; m >>= 1) rv += __shfl_xor(rv, m, 64);
    if (lane == 0) atomicAdd(&IXZ[b], rv);
  }
}

// ---------------- workspace layout (floats) ----------------
constexpr size_t OFF_AMEAN_AP = 0;
constexpr size_t OFF_AMEAN_UE = OFF_AMEAN_AP + BB * D1;
constexpr size_t OFF_STAT_AP  = OFF_AMEAN_UE + BB * D1;
constexpr size_t OFF_STAT_UE  = OFF_STAT_AP + 2 * CH;
constexpr size_t OFF_GATE_AP  = OFF_STAT_UE + 2 * CH;
constexpr size_t OFF_GATE_UE  = OFF_GATE_AP + (size_t)BB * EAP;
constexpr size_t OFF_AAP      = OFF_GATE_UE + (size_t)BB * EUE;
constexpr size_t OFF_AUE      = OFF_AAP + (size_t)BB * D1 * NAP;
constexpr size_t OFF_HM1      = OFF_AUE + (size_t)BB * D1 * NUE;
constexpr size_t OFF_HM2      = OFF_HM1 + (size_t)BB * D2 * NAP;
constexpr size_t OFF_PRE_AP   = OFF_HM2 + (size_t)BB * D2 * NUE;
constexpr size_t OFF_PRE_UE   = OFF_PRE_AP + (size_t)BB * CH * NAP;
constexpr size_t OFF_QB_AP    = OFF_PRE_UE + (size_t)BB * CH * NUE;
constexpr size_t OFF_QB_UE    = OFF_QB_AP + BB * CH;
constexpr size_t OFF_SS_AP    = OFF_QB_UE + BB * CH;
constexpr size_t OFF_SS_UE    = OFF_SS_AP + 2 * CH;
constexpr size_t WS_FLOATS    = OFF_SS_UE + 2 * CH;

extern "C" void kernel_launch(void* const* d_in, const int* in_sizes, int n_in,
                              void* d_out, int out_size, void* d_ws, size_t ws_size,
                              hipStream_t stream)
{
  const float* A_AP  = (const float*)d_in[0];
  const float* A_UE  = (const float*)d_in[1];
  const float* H     = (const float*)d_in[2];
  const float* Q1_AP = (const float*)d_in[3];
  const float* Q2_AP = (const float*)d_in[4];
  const float* Q1_UE = (const float*)d_in[5];
  const float* Q2_UE = (const float*)d_in[6];
  const float* P1_AP = (const float*)d_in[7];
  const float* P1_UE = (const float*)d_in[8];
  const float* AttAP = (const float*)d_in[9];
  const float* AttUE = (const float*)d_in[10];
  const float* bnw   = (const float*)d_in[11];
  const float* bnb   = (const float*)d_in[12];
  const int* GraphAP = (const int*)d_in[13];
  const int* GraphUE = (const int*)d_in[14];
  const int* GFA_AP  = (const int*)d_in[15];
  const int* GFA_UE  = (const int*)d_in[16];

  float* ws = (float*)d_ws;
  if (ws_size < WS_FLOATS * sizeof(float)) return;

  float* amAP  = ws + OFF_AMEAN_AP;
  float* amUE  = ws + OFF_AMEAN_UE;
  float* stAP  = ws + OFF_STAT_AP;
  float* stUE  = ws + OFF_STAT_UE;
  float* gAP   = ws + OFF_GATE_AP;
  float* gUE   = ws + OFF_GATE_UE;
  float* Aap   = ws + OFF_AAP;
  float* Aue   = ws + OFF_AUE;
  float* Hm1   = ws + OFF_HM1;
  float* Hm2   = ws + OFF_HM2;
  float* preAP = ws + OFF_PRE_AP;
  float* preUE = ws + OFF_PRE_UE;
  float* qbAP  = ws + OFF_QB_AP;
  float* qbUE  = ws + OFF_QB_UE;
  float* ssAP  = ws + OFF_SS_AP;
  float* ssUE  = ws + OFF_SS_UE;

  float* out     = (float*)d_out;
  float* outAP   = out;
  float* outUE   = out + (size_t)BB * OUTC * NAP;
  float* IXZ_AP  = out + (size_t)BB * OUTC * (NAP + NUE);
  float* IXZ_UE  = IXZ_AP + BB;
  float* IAZ_AP  = IXZ_UE + BB;
  float* IAZ_UE  = IAZ_AP + BB;

  // 1) per-node scores -> edge gates + KL; also zeros amAP/amUE
  edge_kernel<<<dim3(BB, 2), 256, 0, stream>>>(
      A_AP, A_UE, GraphAP, GraphUE, AttAP, AttUE,
      gAP, gUE, IAZ_AP, IAZ_UE, amAP, amUE);

  // 2) H means (dominant HBM traffic: 256 MB)
  hreduce_kernel<<<BB * D2, 256, 0, stream>>>(H, Hm1, Hm2);

  // 3) aggregation (LDS-staged gathers)
  agg_kernel<NAP, EAP><<<dim3(NAP / 64, BB), 256, 0, stream>>>(
      A_AP, GraphAP, gAP, GFA_AP, Aap, amAP);
  agg_kernel<NUE, EUE><<<dim3(NUE / 64, BB), 256, 0, stream>>>(
      A_UE, GraphUE, gUE, GFA_UE, Aue, amUE);

  // 4) Q2 broadcast terms; also zeros BN stats
  qterm_kernel<<<BB, 128, 0, stream>>>(Q2_AP, Q2_UE, amAP, amUE, qbAP, qbUE, stAP, stUE);

  // 5) einsums + relu + BN stats
  mix_kernel<<<dim3(NAP / 128, 16, BB), 256, 0, stream>>>(
      Aap, Hm1, Q1_AP, P1_AP, qbAP, preAP, stAP, NAP);
  mix_kernel<<<dim3(NUE / 128, 16, BB), 256, 0, stream>>>(
      Aue, Hm2, Q1_UE, P1_UE, qbUE, preUE, stUE, NUE);

  // 6) BN scale/shift; also zeros IXZ accumulators
  bnfinal_kernel<<<1, 256, 0, stream>>>(stAP, stUE, bnw, bnb, ssAP, ssUE, IXZ_AP);

  // 7) normalize + outputs + info_xz
  finalize_kernel<<<dim3(NAP / 64, BB, 2), 256, 0, stream>>>(
      preAP, preUE, ssAP, ssUE, outAP, outUE, IXZ_AP, IXZ_UE);
}

// Round 3
// 669.078 us; speedup vs baseline: 1.3006x; 1.1635x over previous
//
#include <hip/hip_runtime.h>
#include <math.h>

// ---------------- problem constants ----------------
#define BB   64
#define NAP  256
#define NUE  128
#define DEG  32
#define EAP  (NAP*DEG)   // 8192
#define EUE  (NUE*DEG)   // 4096
#define D1   64
#define D2   32
#define OUTC 64
#define CH   128         // 2*OUT
#define SS   10

#define TINYF 1.17549435e-38f
#define LOG_HALF (-0.69314718f)

// ---------------- threefry2x32 (JAX partitionable mode) ----------------
constexpr unsigned rotl_c(unsigned v, int s) { return (v << s) | (v >> (32 - s)); }
struct KeyPair { unsigned hi, lo; };
constexpr KeyPair tf_ck(unsigned k0, unsigned k1, unsigned x0, unsigned x1) {
  unsigned ks2 = k0 ^ k1 ^ 0x1BD11BDAu;
  x0 += k0; x1 += k1;
  const int R[20] = {13,15,26,6, 17,29,16,24, 13,15,26,6, 17,29,16,24, 13,15,26,6};
  const unsigned ia[5] = {k1, ks2, k0, k1, ks2};
  const unsigned ib[5] = {ks2, k0, k1, ks2, k0};
  for (int g = 0; g < 5; ++g) {
    for (int j = 0; j < 4; ++j) { x0 += x1; x1 = rotl_c(x1, R[g*4+j]); x1 ^= x0; }
    x0 += ia[g]; x1 += ib[g] + (unsigned)(g + 1);
  }
  return KeyPair{x0, x1};
}
constexpr KeyPair SK1 = tf_ck(0u, 42u, 0u, 0u);  // logistic noise AP
constexpr KeyPair SK2 = tf_ck(0u, 42u, 0u, 1u);  // logistic noise UE
constexpr KeyPair SK3 = tf_ck(0u, 42u, 0u, 2u);  // normal eps AP
constexpr KeyPair SK4 = tf_ck(0u, 42u, 0u, 3u);  // normal eps UE

__device__ __forceinline__ unsigned rb32(unsigned k0, unsigned k1, unsigned ctr) {
  const unsigned ks2 = k0 ^ k1 ^ 0x1BD11BDAu;
  unsigned x0 = k0;
  unsigned x1 = ctr + k1;
#define TFR(r) { x0 += x1; x1 = (x1 << r) | (x1 >> (32 - r)); x1 ^= x0; }
  TFR(13) TFR(15) TFR(26) TFR(6)
  x0 += k1;  x1 += ks2 + 1u;
  TFR(17) TFR(29) TFR(16) TFR(24)
  x0 += ks2; x1 += k0 + 2u;
  TFR(13) TFR(15) TFR(26) TFR(6)
  x0 += k0;  x1 += k1 + 3u;
  TFR(17) TFR(29) TFR(16) TFR(24)
  x0 += k1;  x1 += ks2 + 4u;
  TFR(13) TFR(15) TFR(26) TFR(6)
  x0 += ks2; x1 += k0 + 5u;
#undef TFR
  return x0 ^ x1;
}

__device__ __forceinline__ float bits_to_unit(unsigned bits) {
  return __uint_as_float((bits >> 9) | 0x3f800000u) - 1.0f;
}

// XLA ErfInv32 (Giles polynomial)
__device__ __forceinline__ float erfinv_f32(float x) {
  float w = -log1pf(-x * x);
  float p;
  if (w < 5.0f) {
    w = w - 2.5f;
    p = 2.81022636e-08f;
    p = fmaf(p, w, 3.43273939e-07f);
    p = fmaf(p, w, -3.5233877e-06f);
    p = fmaf(p, w, -4.39150654e-06f);
    p = fmaf(p, w, 0.00021858087f);
    p = fmaf(p, w, -0.00125372503f);
    p = fmaf(p, w, -0.00417768164f);
    p = fmaf(p, w, 0.246640727f);
    p = fmaf(p, w, 1.50140941f);
  } else {
    w = sqrtf(w) - 3.0f;
    p = -0.000200214257f;
    p = fmaf(p, w, 0.000100950558f);
    p = fmaf(p, w, 0.00134934322f);
    p = fmaf(p, w, -0.00367342844f);
    p = fmaf(p, w, 0.00573950773f);
    p = fmaf(p, w, -0.0076224613f);
    p = fmaf(p, w, 0.00943887047f);
    p = fmaf(p, w, 1.00167406f);
    p = fmaf(p, w, 2.83297682f);
  }
  return p * x;
}

__device__ __forceinline__ float normal_from_bits(unsigned bits) {
  float f = bits_to_unit(bits);
  const float lo = -0.99999994f;
  float u = fmaxf(lo, fmaf(f, 2.0f, lo));
  return 1.41421354f * erfinv_f32(u);
}

__device__ __forceinline__ float softplus_f(float x) {
  return fmaxf(x, 0.0f) + log1pf(expf(-fabsf(x)));
}

// ---------------- kernel 1: per-node scores -> edge gate + KL ----------------
__global__ __launch_bounds__(256) void edge_kernel(
    const float* __restrict__ A_AP, const float* __restrict__ A_UE,
    const int* __restrict__ GAP, const int* __restrict__ GUE,
    const float* __restrict__ AttAP, const float* __restrict__ AttUE,
    float* __restrict__ gAP, float* __restrict__ gUE,
    float* __restrict__ IAZ_AP, float* __restrict__ IAZ_UE,
    float* __restrict__ amAP, float* __restrict__ amUE)
{
  const int side = blockIdx.y;
  const int b = blockIdx.x;
  const int N = side ? NUE : NAP;
  const int E = side ? EUE : EAP;
  const float* A  = (side ? A_UE : A_AP) + (size_t)b * D1 * N;
  const int* G    = (side ? GUE : GAP) + (size_t)b * 2 * E;
  const float* At = side ? AttUE : AttAP;
  float* gate     = (side ? gUE : gAP) + (size_t)b * E;
  float* IAZ      = side ? IAZ_UE : IAZ_AP;
  float* am       = side ? amUE : amAP;
  const unsigned k0 = side ? SK2.hi : SK1.hi;
  const unsigned k1 = side ? SK2.lo : SK1.lo;
  const int t = threadIdx.x;

  if (t < D1) am[b * D1 + t] = 0.f;   // zero amean accumulator for agg

  __shared__ float si_s[NAP];
  __shared__ float sj_s[NAP];
  if (t < N) {
    float a0 = 0.f, a1 = 0.f;
    #pragma unroll
    for (int d = 0; d < D1; ++d) {
      float v = A[d * N + t];
      a0 = fmaf(v, At[d], a0);
      a1 = fmaf(v, At[D1 + d], a1);
    }
    si_s[t] = a0; sj_s[t] = a1;
  }
  __syncthreads();

  float klacc = 0.f;
  for (int e = t; e < E; e += 256) {
    const int ii = G[E + e];   // Graph[:,1] -> x_i
    const int jj = G[e];       // Graph[:,0] -> x_j
    float score = si_s[ii] + sj_s[jj];
    float l = (score >= 0.f) ? score : 0.2f * score;
    float sig = 1.f / (1.f + expf(-l));
    float a = fminf(fmaxf(sig, 0.01f), 0.99f);
    float logits = logf(a) - log1pf(-a);
    unsigned bits = rb32(k0, k1, (unsigned)(b * E + e));
    float f = bits_to_unit(bits);
    float u = fmaxf(TINYF, f + TINYF);
    float noise = logf(u) - log1pf(-u);
    float gv = 1.f / (1.f + expf(-((logits + noise) / 0.1f)));
    gate[e] = gv;
    klacc += a * (logf(a) - LOG_HALF) + (1.f - a) * (log1pf(-a) - LOG_HALF);
  }
  #pragma unroll
  for (int m = 32; m; m >>= 1) klacc += __shfl_xor(klacc, m, 64);
  __shared__ float red[4];
  if ((t & 63) == 0) red[t >> 6] = klacc;
  __syncthreads();
  if (t == 0) IAZ[b] = red[0] + red[1] + red[2] + red[3];
}

// ---------------- kernel 2: degree-32 aggregation (AP+UE combined), LDS gathers ----------------
__global__ __launch_bounds__(256) void agg_kernel(
    const float* __restrict__ A_AP, const float* __restrict__ A_UE,
    const int* __restrict__ GAP, const int* __restrict__ GUE,
    const float* __restrict__ gAP, const float* __restrict__ gUE,
    const int* __restrict__ GFA_AP, const int* __restrict__ GFA_UE,
    float* __restrict__ Aap, float* __restrict__ Aue,
    float* __restrict__ amAP, float* __restrict__ amUE)
{
  __shared__ float Als[D1 * NAP];     // 64 KB (UE blocks use first half)
  const int x = blockIdx.x;
  const int side = (x >= NAP / 64);   // 0..3 AP, 4..5 UE
  const int tile = side ? x - NAP / 64 : x;
  const int b = blockIdx.y;
  const int N = side ? NUE : NAP;
  const int E = side ? EUE : EAP;
  const float* A  = (side ? A_UE : A_AP) + (size_t)b * D1 * N;
  const int* G0   = (side ? GUE : GAP) + (size_t)b * 2 * E;
  const float* gb = (side ? gUE : gAP) + (size_t)b * E;
  float* Aout = side ? Aue : Aap;
  float* am   = side ? amUE : amAP;

  const int t = threadIdx.x;
  const int wave = t >> 6, lane = t & 63;
  const int n = tile * 64 + lane;

  const int* gfa = (side ? GFA_UE : GFA_AP) + ((size_t)b * N + n) * DEG;
  int jj[DEG]; float gg[DEG];
  #pragma unroll
  for (int k = 0; k < DEG; ++k) {
    int e = gfa[k];
    jj[k] = G0[e];
    gg[k] = gb[e];
  }

  for (int idx = t * 4; idx < D1 * N; idx += 1024)
    *(float4*)(Als + idx) = *(const float4*)(A + idx);
  __syncthreads();

  for (int dd = 0; dd < 16; ++dd) {
    const int d = wave * 16 + dd;
    const float* Ar = Als + d * N;
    float acc = 0.f;
    #pragma unroll
    for (int k = 0; k < DEG; ++k) acc = fmaf(gg[k], Ar[jj[k]], acc);
    Aout[((size_t)b * D1 + d) * N + n] = acc;
    float s = acc;
    #pragma unroll
    for (int m = 32; m; m >>= 1) s += __shfl_xor(s, m, 64);
    if (lane == 0) atomicAdd(&am[b * D1 + d], s);
  }
}

// ---------------- kernel 3: H -> mean over NUE (Hm1) and over NAP (Hm2) ----------------
__global__ __launch_bounds__(256) void hreduce_kernel(
    const float* __restrict__ H, float* __restrict__ Hm1, float* __restrict__ Hm2)
{
  const int bd = blockIdx.x;                         // b*D2 + d2
  const float* Hp = H + (size_t)bd * NAP * NUE;
  const int t = threadIdx.x;
  const int tx = t & 31, ty = t >> 5;
  float4 col = {0.f, 0.f, 0.f, 0.f};
  #pragma unroll 4
  for (int i = ty; i < NAP; i += 8) {
    float4 v = ((const float4*)(Hp + (size_t)i * NUE))[tx];
    col.x += v.x; col.y += v.y; col.z += v.z; col.w += v.w;
    float rs = v.x + v.y + v.z + v.w;
    #pragma unroll
    for (int m = 16; m; m >>= 1) rs += __shfl_xor(rs, m, 64);
    if (tx == 0) Hm1[(size_t)bd * NAP + i] = rs * (1.0f / NUE);
  }
  __shared__ float cp[8 * 128];
  ((float4*)cp)[ty * 32 + tx] = col;
  __syncthreads();
  if (t < 128) {
    float s = 0.f;
    #pragma unroll
    for (int r = 0; r < 8; ++r) s += cp[r * 128 + t];
    Hm2[(size_t)bd * NUE + t] = s * (1.0f / NAP);
  }
}

// ---------------- kernel 4: broadcast Q2 term (+ zero BN stats) ----------------
__global__ __launch_bounds__(128) void qterm_kernel(
    const float* __restrict__ Q2_AP, const float* __restrict__ Q2_UE,
    const float* __restrict__ AapMeanRaw, const float* __restrict__ AueMeanRaw,
    float* __restrict__ qbAP, float* __restrict__ qbUE,
    float* __restrict__ stAP, float* __restrict__ stUE)
{
  const int b = blockIdx.x;
  const int o = threadIdx.x;
  if (b == 0) {
    #pragma unroll
    for (int i = o; i < 2 * CH; i += 128) { stAP[i] = 0.f; stUE[i] = 0.f; }
  }
  float sA = 0.f, sU = 0.f;
  #pragma unroll
  for (int d = 0; d < D1; ++d) {
    float mUE = AueMeanRaw[b * D1 + d] * (1.0f / NUE);
    float mAP = AapMeanRaw[b * D1 + d] * (1.0f / NAP);
    sA = fmaf(Q2_AP[o * D1 + d], mUE, sA);
    sU = fmaf(Q2_UE[o * D1 + d], mAP, sU);
  }
  qbAP[b * CH + o] = 2.f * sA;
  qbUE[b * CH + o] = 2.f * sU;
}

// ---------------- kernel 5: combined einsums + relu + BN stats (register-tiled) ----------------
// grid (6, BB): x<4 -> AP tile x (64 n), x>=4 -> UE tile x-4. block 256.
// thread: tn = t&15 (4 n via float4), to = t>>4 (8 o) -> 8o x 4n register tile.
__global__ __launch_bounds__(256) void mix_kernel(
    const float* __restrict__ Aap, const float* __restrict__ Aue,
    const float* __restrict__ Hm1, const float* __restrict__ Hm2,
    const float* __restrict__ Q1_AP, const float* __restrict__ Q1_UE,
    const float* __restrict__ P1_AP, const float* __restrict__ P1_UE,
    const float* __restrict__ qbAP, const float* __restrict__ qbUE,
    float* __restrict__ preAP, float* __restrict__ preUE,
    float* __restrict__ stAP, float* __restrict__ stUE)
{
  __shared__ float Qs[CH * 65];   // pad 65: bank = (o+d)%32, conflict-free
  __shared__ float Ps[CH * 33];   // pad 33: bank = (o+c)%32
  __shared__ float As[D1 * 64];
  __shared__ float Hs[D2 * 64];
  const int x = blockIdx.x;
  const int side = (x >= NAP / 64);
  const int tile = side ? x - NAP / 64 : x;
  const int b = blockIdx.y;
  const int N = side ? NUE : NAP;
  const float* Aagg = (side ? Aue : Aap) + (size_t)b * D1 * N + tile * 64;
  const float* Hm   = (side ? Hm2 : Hm1) + (size_t)b * D2 * N + tile * 64;
  const float* Q1   = side ? Q1_UE : Q1_AP;
  const float* P1   = side ? P1_UE : P1_AP;
  const float* qb   = (side ? qbUE : qbAP) + b * CH;
  float* pre        = (side ? preUE : preAP) + (size_t)b * CH * N + tile * 64;
  float* stat       = side ? stUE : stAP;

  const int t = threadIdx.x;
  for (int i = t; i < CH * D1; i += 256) Qs[(i >> 6) * 65 + (i & 63)] = Q1[i];
  for (int i = t; i < CH * D2; i += 256) Ps[(i >> 5) * 33 + (i & 31)] = P1[i];
  for (int i = t; i < D1 * 64; i += 256) As[i] = Aagg[(size_t)(i >> 6) * N + (i & 63)];
  for (int i = t; i < D2 * 64; i += 256) Hs[i] = Hm[(size_t)(i >> 6) * N + (i & 63)];
  __syncthreads();

  const int tn = t & 15, to = t >> 4;
  float accQ[8][4] = {};
  for (int d = 0; d < D1; ++d) {
    float4 a = *(const float4*)&As[d * 64 + tn * 4];
    #pragma unroll
    for (int oi = 0; oi < 8; ++oi) {
      float w = Qs[(to * 8 + oi) * 65 + d];
      accQ[oi][0] = fmaf(w, a.x, accQ[oi][0]);
      accQ[oi][1] = fmaf(w, a.y, accQ[oi][1]);
      accQ[oi][2] = fmaf(w, a.z, accQ[oi][2]);
      accQ[oi][3] = fmaf(w, a.w, accQ[oi][3]);
    }
  }
  float accP[8][4] = {};
  for (int c = 0; c < D2; ++c) {
    float4 h = *(const float4*)&Hs[c * 64 + tn * 4];
    #pragma unroll
    for (int oi = 0; oi < 8; ++oi) {
      float w = Ps[(to * 8 + oi) * 33 + c];
      accP[oi][0] = fmaf(w, h.x, accP[oi][0]);
      accP[oi][1] = fmaf(w, h.y, accP[oi][1]);
      accP[oi][2] = fmaf(w, h.z, accP[oi][2]);
      accP[oi][3] = fmaf(w, h.w, accP[oi][3]);
    }
  }
  #pragma unroll
  for (int oi = 0; oi < 8; ++oi) {
    const int o = to * 8 + oi;
    const float base = qb[o];
    float4 r;
    r.x = fmaxf(2.f * accQ[oi][0] + base + 0.1f * accP[oi][0], 0.f);
    r.y = fmaxf(2.f * accQ[oi][1] + base + 0.1f * accP[oi][1], 0.f);
    r.z = fmaxf(2.f * accQ[oi][2] + base + 0.1f * accP[oi][2], 0.f);
    r.w = fmaxf(2.f * accQ[oi][3] + base + 0.1f * accP[oi][3], 0.f);
    *(float4*)&pre[(size_t)o * N + tn * 4] = r;
    float s1 = r.x + r.y + r.z + r.w;
    float s2 = r.x * r.x + r.y * r.y + r.z * r.z + r.w * r.w;
    #pragma unroll
    for (int m = 1; m < 16; m <<= 1) { s1 += __shfl_xor(s1, m, 64); s2 += __shfl_xor(s2, m, 64); }
    if (tn == 0) { atomicAdd(&stat[o], s1); atomicAdd(&stat[CH + o], s2); }
  }
}

// ---------------- kernel 6: BN scale/shift (+ zero IXZ accumulators) ----------------
__global__ __launch_bounds__(256) void bnfinal_kernel(
    const float* __restrict__ statAP, const float* __restrict__ statUE,
    const float* __restrict__ bnw, const float* __restrict__ bnb,
    float* __restrict__ ssAP, float* __restrict__ ssUE,
    float* __restrict__ IXZ)
{
  const int t = threadIdx.x;
  if (t < 2 * BB) IXZ[t] = 0.f;
  if (t < CH) {
    const float inv = 1.0f / (BB * NAP);
    float m = statAP[t] * inv;
    float v = statAP[CH + t] * inv - m * m;
    float sc = bnw[t] / sqrtf(v + 1e-5f);
    ssAP[t] = sc; ssAP[CH + t] = bnb[t] - m * sc;
  } else {
    const int o = t - CH;
    const float inv = 1.0f / (BB * NUE);
    float m = statUE[o] * inv;
    float v = statUE[CH + o] * inv - m * m;
    float sc = bnw[o] / sqrtf(v + 1e-5f);
    ssUE[o] = sc; ssUE[CH + o] = bnb[o] - m * sc;
  }
}

// ---------------- kernel 7: normalize + outputs + info_xz ----------------
__global__ __launch_bounds__(256) void finalize_kernel(
    const float* __restrict__ preAP, const float* __restrict__ preUE,
    const float* __restrict__ ssAP, const float* __restrict__ ssUE,
    float* __restrict__ outAP, float* __restrict__ outUE,
    float* __restrict__ IXZAP, float* __restrict__ IXZUE)
{
  const int side = blockIdx.z;
  const int N = side ? NUE : NAP;
  if ((int)blockIdx.x * 64 >= N) return;
  const float* pre = side ? preUE : preAP;
  const float* ss  = side ? ssUE  : ssAP;
  float* outp      = side ? outUE : outAP;
  float* IXZ       = side ? IXZUE : IXZAP;
  const unsigned k0 = side ? SK4.hi : SK3.hi;
  const unsigned k1 = side ? SK4.lo : SK3.lo;
  const int ROWS = BB * N;

  const int b = blockIdx.y;
  const int lane = threadIdx.x & 63;
  const int og = threadIdx.x >> 6;
  const int n = blockIdx.x * 64 + lane;
  const int row = b * N + n;
  const float* preb = pre + (size_t)b * CH * N;

  float accZ = 0.f, sumlog = 0.f;
  for (int oi = 0; oi < 16; ++oi) {
    const int o = og * 16 + oi;
    float mpre = preb[o * N + n];
    float rraw = preb[(o + 64) * N + n];
    float x0 = fmaf(mpre, ss[o], ss[CH + o]);
    float x1 = fmaf(rraw, ss[o + 64], ss[CH + o + 64]);
    outp[((size_t)b * OUTC + o) * N + n] = x0;
    float stdv = softplus_f(x1) + 1e-10f;
    sumlog += logf(stdv);
    #pragma unroll
    for (int s = 0; s < SS; ++s) {
      unsigned idx = (unsigned)((s * ROWS + row) * 64 + o);
      float eps = normal_from_bits(rb32(k0, k1, idx));
      float Z = fmaf(stdv, eps, x0);
      accZ += 0.5f * (Z * Z - eps * eps);
    }
  }
  __shared__ float pz[4][64];
  __shared__ float pl[4][64];
  pz[og][lane] = accZ; pl[og][lane] = sumlog;
  __syncthreads();
  if (og == 0) {
    float az = pz[0][lane] + pz[1][lane] + pz[2][lane] + pz[3][lane];
    float al = pl[0][lane] + pl[1][lane] + pl[2][lane] + pl[3][lane];
    float rv = az * (1.0f / SS) - al;
    #pragma unroll
    for (int m = 32; m; m >>= 1) rv += __shfl_xor(rv, m, 64);
    if (lane == 0) atomicAdd(&IXZ[b], rv);
  }
}

// ---------------- workspace layout (floats) ----------------
constexpr size_t OFF_AMEAN_AP = 0;
constexpr size_t OFF_AMEAN_UE = OFF_AMEAN_AP + BB * D1;
constexpr size_t OFF_STAT_AP  = OFF_AMEAN_UE + BB * D1;
constexpr size_t OFF_STAT_UE  = OFF_STAT_AP + 2 * CH;
constexpr size_t OFF_GATE_AP  = OFF_STAT_UE + 2 * CH;
constexpr size_t OFF_GATE_UE  = OFF_GATE_AP + (size_t)BB * EAP;
constexpr size_t OFF_AAP      = OFF_GATE_UE + (size_t)BB * EUE;
constexpr size_t OFF_AUE      = OFF_AAP + (size_t)BB * D1 * NAP;
constexpr size_t OFF_HM1      = OFF_AUE + (size_t)BB * D1 * NUE;
constexpr size_t OFF_HM2      = OFF_HM1 + (size_t)BB * D2 * NAP;
constexpr size_t OFF_PRE_AP   = OFF_HM2 + (size_t)BB * D2 * NUE;
constexpr size_t OFF_PRE_UE   = OFF_PRE_AP + (size_t)BB * CH * NAP;
constexpr size_t OFF_QB_AP    = OFF_PRE_UE + (size_t)BB * CH * NUE;
constexpr size_t OFF_QB_UE    = OFF_QB_AP + BB * CH;
constexpr size_t OFF_SS_AP    = OFF_QB_UE + BB * CH;
constexpr size_t OFF_SS_UE    = OFF_SS_AP + 2 * CH;
constexpr size_t WS_FLOATS    = OFF_SS_UE + 2 * CH;

extern "C" void kernel_launch(void* const* d_in, const int* in_sizes, int n_in,
                              void* d_out, int out_size, void* d_ws, size_t ws_size,
                              hipStream_t stream)
{
  const float* A_AP  = (const float*)d_in[0];
  const float* A_UE  = (const float*)d_in[1];
  const float* H     = (const float*)d_in[2];
  const float* Q1_AP = (const float*)d_in[3];
  const float* Q2_AP = (const float*)d_in[4];
  const float* Q1_UE = (const float*)d_in[5];
  const float* Q2_UE = (const float*)d_in[6];
  const float* P1_AP = (const float*)d_in[7];
  const float* P1_UE = (const float*)d_in[8];
  const float* AttAP = (const float*)d_in[9];
  const float* AttUE = (const float*)d_in[10];
  const float* bnw   = (const float*)d_in[11];
  const float* bnb   = (const float*)d_in[12];
  const int* GraphAP = (const int*)d_in[13];
  const int* GraphUE = (const int*)d_in[14];
  const int* GFA_AP  = (const int*)d_in[15];
  const int* GFA_UE  = (const int*)d_in[16];

  float* ws = (float*)d_ws;
  if (ws_size < WS_FLOATS * sizeof(float)) return;

  float* amAP  = ws + OFF_AMEAN_AP;
  float* amUE  = ws + OFF_AMEAN_UE;
  float* stAP  = ws + OFF_STAT_AP;
  float* stUE  = ws + OFF_STAT_UE;
  float* gAP   = ws + OFF_GATE_AP;
  float* gUE   = ws + OFF_GATE_UE;
  float* Aap   = ws + OFF_AAP;
  float* Aue   = ws + OFF_AUE;
  float* Hm1   = ws + OFF_HM1;
  float* Hm2   = ws + OFF_HM2;
  float* preAP = ws + OFF_PRE_AP;
  float* preUE = ws + OFF_PRE_UE;
  float* qbAP  = ws + OFF_QB_AP;
  float* qbUE  = ws + OFF_QB_UE;
  float* ssAP  = ws + OFF_SS_AP;
  float* ssUE  = ws + OFF_SS_UE;

  float* out     = (float*)d_out;
  float* outAP   = out;
  float* outUE   = out + (size_t)BB * OUTC * NAP;
  float* IXZ_AP  = out + (size_t)BB * OUTC * (NAP + NUE);
  float* IXZ_UE  = IXZ_AP + BB;
  float* IAZ_AP  = IXZ_UE + BB;
  float* IAZ_UE  = IAZ_AP + BB;

  // 1) per-node scores -> edge gates + KL; also zeros amAP/amUE
  edge_kernel<<<dim3(BB, 2), 256, 0, stream>>>(
      A_AP, A_UE, GraphAP, GraphUE, AttAP, AttUE,
      gAP, gUE, IAZ_AP, IAZ_UE, amAP, amUE);

  // 2) H means (dominant HBM traffic: 256 MB)
  hreduce_kernel<<<BB * D2, 256, 0, stream>>>(H, Hm1, Hm2);

  // 3) aggregation, AP+UE in one launch (LDS-staged gathers)
  agg_kernel<<<dim3(NAP / 64 + NUE / 64, BB), 256, 0, stream>>>(
      A_AP, A_UE, GraphAP, GraphUE, gAP, gUE, GFA_AP, GFA_UE,
      Aap, Aue, amAP, amUE);

  // 4) Q2 broadcast terms; also zeros BN stats
  qterm_kernel<<<BB, 128, 0, stream>>>(Q2_AP, Q2_UE, amAP, amUE, qbAP, qbUE, stAP, stUE);

  // 5) combined einsums + relu + BN stats
  mix_kernel<<<dim3(NAP / 64 + NUE / 64, BB), 256, 0, stream>>>(
      Aap, Aue, Hm1, Hm2, Q1_AP, Q1_UE, P1_AP, P1_UE,
      qbAP, qbUE, preAP, preUE, stAP, stUE);

  // 6) BN scale/shift; also zeros IXZ accumulators
  bnfinal_kernel<<<1, 256, 0, stream>>>(stAP, stUE, bnw, bnb, ssAP, ssUE, IXZ_AP);

  // 7) normalize + outputs + info_xz
  finalize_kernel<<<dim3(NAP / 64, BB, 2), 256, 0, stream>>>(
      preAP, preUE, ssAP, ssUE, outAP, outUE, IXZ_AP, IXZ_UE);
}

// Round 4
// 645.539 us; speedup vs baseline: 1.3481x; 1.0365x over previous
//
#include <hip/hip_runtime.h>
#include <math.h>

// ---------------- problem constants ----------------
#define BB   64
#define NAP  256
#define NUE  128
#define DEG  32
#define EAP  (NAP*DEG)   // 8192
#define EUE  (NUE*DEG)   // 4096
#define D1   64
#define D2   32
#define OUTC 64
#define CH   128         // 2*OUT
#define SS   10
#define NEB  (BB*2)      // edge+agg blocks in K1

#define TINYF 1.17549435e-38f
#define LOG_HALF (-0.69314718f)

// ---------------- threefry2x32 (JAX partitionable mode) ----------------
constexpr unsigned rotl_c(unsigned v, int s) { return (v << s) | (v >> (32 - s)); }
struct KeyPair { unsigned hi, lo; };
constexpr KeyPair tf_ck(unsigned k0, unsigned k1, unsigned x0, unsigned x1) {
  unsigned ks2 = k0 ^ k1 ^ 0x1BD11BDAu;
  x0 += k0; x1 += k1;
  const int R[20] = {13,15,26,6, 17,29,16,24, 13,15,26,6, 17,29,16,24, 13,15,26,6};
  const unsigned ia[5] = {k1, ks2, k0, k1, ks2};
  const unsigned ib[5] = {ks2, k0, k1, ks2, k0};
  for (int g = 0; g < 5; ++g) {
    for (int j = 0; j < 4; ++j) { x0 += x1; x1 = rotl_c(x1, R[g*4+j]); x1 ^= x0; }
    x0 += ia[g]; x1 += ib[g] + (unsigned)(g + 1);
  }
  return KeyPair{x0, x1};
}
constexpr KeyPair SK1 = tf_ck(0u, 42u, 0u, 0u);  // logistic noise AP
constexpr KeyPair SK2 = tf_ck(0u, 42u, 0u, 1u);  // logistic noise UE
constexpr KeyPair SK3 = tf_ck(0u, 42u, 0u, 2u);  // normal eps AP
constexpr KeyPair SK4 = tf_ck(0u, 42u, 0u, 3u);  // normal eps UE

__device__ __forceinline__ unsigned rb32(unsigned k0, unsigned k1, unsigned ctr) {
  const unsigned ks2 = k0 ^ k1 ^ 0x1BD11BDAu;
  unsigned x0 = k0;
  unsigned x1 = ctr + k1;
#define TFR(r) { x0 += x1; x1 = (x1 << r) | (x1 >> (32 - r)); x1 ^= x0; }
  TFR(13) TFR(15) TFR(26) TFR(6)
  x0 += k1;  x1 += ks2 + 1u;
  TFR(17) TFR(29) TFR(16) TFR(24)
  x0 += ks2; x1 += k0 + 2u;
  TFR(13) TFR(15) TFR(26) TFR(6)
  x0 += k0;  x1 += k1 + 3u;
  TFR(17) TFR(29) TFR(16) TFR(24)
  x0 += k1;  x1 += ks2 + 4u;
  TFR(13) TFR(15) TFR(26) TFR(6)
  x0 += ks2; x1 += k0 + 5u;
#undef TFR
  return x0 ^ x1;
}

__device__ __forceinline__ float bits_to_unit(unsigned bits) {
  return __uint_as_float((bits >> 9) | 0x3f800000u) - 1.0f;
}

// XLA ErfInv32 (Giles polynomial)
__device__ __forceinline__ float erfinv_f32(float x) {
  float w = -log1pf(-x * x);
  float p;
  if (w < 5.0f) {
    w = w - 2.5f;
    p = 2.81022636e-08f;
    p = fmaf(p, w, 3.43273939e-07f);
    p = fmaf(p, w, -3.5233877e-06f);
    p = fmaf(p, w, -4.39150654e-06f);
    p = fmaf(p, w, 0.00021858087f);
    p = fmaf(p, w, -0.00125372503f);
    p = fmaf(p, w, -0.00417768164f);
    p = fmaf(p, w, 0.246640727f);
    p = fmaf(p, w, 1.50140941f);
  } else {
    w = sqrtf(w) - 3.0f;
    p = -0.000200214257f;
    p = fmaf(p, w, 0.000100950558f);
    p = fmaf(p, w, 0.00134934322f);
    p = fmaf(p, w, -0.00367342844f);
    p = fmaf(p, w, 0.00573950773f);
    p = fmaf(p, w, -0.0076224613f);
    p = fmaf(p, w, 0.00943887047f);
    p = fmaf(p, w, 1.00167406f);
    p = fmaf(p, w, 2.83297682f);
  }
  return p * x;
}

__device__ __forceinline__ float normal_from_bits(unsigned bits) {
  float f = bits_to_unit(bits);
  const float lo = -0.99999994f;
  float u = fmaxf(lo, fmaf(f, 2.0f, lo));
  return 1.41421354f * erfinv_f32(u);
}

__device__ __forceinline__ float softplus_f(float x) {
  return fmaxf(x, 0.0f) + log1pf(expf(-fabsf(x)));
}

__device__ __forceinline__ float gate_of(float score, unsigned k0, unsigned k1, unsigned ctr) {
  float l = (score >= 0.f) ? score : 0.2f * score;
  float sig = 1.f / (1.f + expf(-l));
  float a = fminf(fmaxf(sig, 0.01f), 0.99f);
  float logits = logf(a) - log1pf(-a);
  unsigned bits = rb32(k0, k1, ctr);
  float f = bits_to_unit(bits);
  float u = fmaxf(TINYF, f + TINYF);
  float noise = logf(u) - log1pf(-u);
  return 1.f / (1.f + expf(-((logits + noise) / 0.1f)));
}

// ---------------- K1 part A: H -> mean over NUE (Hm1) and over NAP (Hm2) ----------------
__device__ __forceinline__ void hreduce_body(int bd, float* cp,
    const float* __restrict__ H, float* __restrict__ Hm1, float* __restrict__ Hm2)
{
  const float* Hp = H + (size_t)bd * NAP * NUE;
  const int t = threadIdx.x;
  const int tx = t & 31, ty = t >> 5;
  float4 col = {0.f, 0.f, 0.f, 0.f};
  #pragma unroll 4
  for (int i = ty; i < NAP; i += 8) {
    float4 v = ((const float4*)(Hp + (size_t)i * NUE))[tx];
    col.x += v.x; col.y += v.y; col.z += v.z; col.w += v.w;
    float rs = v.x + v.y + v.z + v.w;
    #pragma unroll
    for (int m = 16; m; m >>= 1) rs += __shfl_xor(rs, m, 64);
    if (tx == 0) Hm1[(size_t)bd * NAP + i] = rs * (1.0f / NUE);
  }
  ((float4*)cp)[ty * 32 + tx] = col;
  __syncthreads();
  if (t < 128) {
    float s = 0.f;
    #pragma unroll
    for (int r = 0; r < 8; ++r) s += cp[r * 128 + t];
    Hm2[(size_t)bd * NUE + t] = s * (1.0f / NAP);
  }
}

// ---------------- K1: [edge scores + KL + gates + aggregation] || [H means] ----------------
__global__ __launch_bounds__(256) void k1_kernel(
    const float* __restrict__ A_AP, const float* __restrict__ A_UE,
    const float* __restrict__ H,
    const int* __restrict__ GAP, const int* __restrict__ GUE,
    const float* __restrict__ AttAP, const float* __restrict__ AttUE,
    const int* __restrict__ GFA_AP, const int* __restrict__ GFA_UE,
    float* __restrict__ Aap, float* __restrict__ Aue,
    float* __restrict__ amAP, float* __restrict__ amUE,
    float* __restrict__ Hm1, float* __restrict__ Hm2,
    float* __restrict__ IAZ_AP, float* __restrict__ IAZ_UE,
    float* __restrict__ stat0, float* __restrict__ IXZ0)
{
  __shared__ float smem[8192 + NAP + NAP + D1];   // ~35 KB
  __shared__ float red2[4];
  const int x = blockIdx.x;
  const int t = threadIdx.x;
  if (x >= NEB) { hreduce_body(x - NEB, smem, H, Hm1, Hm2); return; }

  if (x == 0) {
    for (int i = t; i < 4 * CH; i += 256) stat0[i] = 0.f;   // stAP + stUE (contiguous)
    for (int i = t; i < 2 * BB; i += 256) IXZ0[i] = 0.f;
  }
  const int side = x & 1, b = x >> 1;
  const int N = side ? NUE : NAP;
  const int E = N * DEG;
  const float* A  = (side ? A_UE : A_AP) + (size_t)b * D1 * N;
  const int* G    = (side ? GUE : GAP) + (size_t)b * 2 * E;
  const float* At = side ? AttUE : AttAP;
  const int* gfa  = (side ? GFA_UE : GFA_AP) + (size_t)b * N * DEG;
  float* Aout = (side ? Aue : Aap) + (size_t)b * D1 * N;
  float* am   = (side ? amUE : amAP) + b * D1;
  float* IAZ  = side ? IAZ_UE : IAZ_AP;
  const unsigned k0 = side ? SK2.hi : SK1.hi;
  const unsigned k1 = side ? SK2.lo : SK1.lo;

  float* Als  = smem;               // 8192: A rows staged in 32-row halves (AP) / all 64 (UE)
  float* si_s = smem + 8192;        // NAP
  float* sj_s = si_s + NAP;         // NAP
  float* am_s = sj_s + NAP;         // D1

  if (t < D1) am_s[t] = 0.f;
  // per-node scores, from global (coalesced; same fmaf chain as reference path)
  if (t < N) {
    float a0 = 0.f, a1 = 0.f;
    #pragma unroll
    for (int d = 0; d < D1; ++d) {
      float v = A[d * N + t];
      a0 = fmaf(v, At[d], a0);
      a1 = fmaf(v, At[D1 + d], a1);
    }
    si_s[t] = a0; sj_s[t] = a1;
  }
  __syncthreads();

  // KL over ALL E edges (alpha only; no RNG needed)
  float klacc = 0.f;
  for (int e = t; e < E; e += 256) {
    float score = si_s[G[E + e]] + sj_s[G[e]];
    float l = (score >= 0.f) ? score : 0.2f * score;
    float sig = 1.f / (1.f + expf(-l));
    float a = fminf(fmaxf(sig, 0.01f), 0.99f);
    klacc += a * (logf(a) - LOG_HALF) + (1.f - a) * (log1pf(-a) - LOG_HALF);
  }
  #pragma unroll
  for (int m = 32; m; m >>= 1) klacc += __shfl_xor(klacc, m, 64);
  if ((t & 63) == 0) red2[t >> 6] = klacc;
  __syncthreads();
  if (t == 0) IAZ[b] = red2[0] + red2[1] + red2[2] + red2[3];

  // gather edge list + compute gates inline (exactly E gate evaluations; deterministic RNG)
  int jj[DEG]; float gv[DEG];
  if (t < N) {
    const int* gf = gfa + t * DEG;
    #pragma unroll
    for (int k = 0; k < DEG; ++k) {
      int e = gf[k];
      int ii = G[E + e];
      jj[k] = G[e];
      float score = si_s[ii] + sj_s[jj[k]];
      gv[k] = gate_of(score, k0, k1, (unsigned)(b * E + e));
    }
  }

  // aggregation over d, A staged in halves of 8192 floats
  const int HR = side ? D1 : 32;         // rows per stage (UE: all 64; AP: 32+32)
  const int halves = side ? 1 : 2;
  for (int h = 0; h < halves; ++h) {
    __syncthreads();
    const float* Ah = A + (size_t)h * HR * N;
    for (int idx = t * 4; idx < HR * N; idx += 1024)
      *(float4*)(Als + idx) = *(const float4*)(Ah + idx);
    __syncthreads();
    if (t < N) {
      for (int dr = 0; dr < HR; ++dr) {
        const int d = h * HR + dr;
        const float* Ar = Als + dr * N;
        float acc = 0.f;
        #pragma unroll
        for (int k = 0; k < DEG; ++k) acc = fmaf(gv[k], Ar[jj[k]], acc);
        Aout[(size_t)d * N + t] = acc;
        float s = acc;
        #pragma unroll
        for (int m = 32; m; m >>= 1) s += __shfl_xor(s, m, 64);
        if ((t & 63) == 0) atomicAdd(&am_s[d], s);
      }
    }
  }
  __syncthreads();
  if (t < D1) am[t] = am_s[t];   // single writer block per (b,side): direct store
}

// ---------------- K2: inline qb + einsums + relu + BN stats ----------------
// grid (6, BB): x<4 -> AP tile x (64 n), x>=4 -> UE tile x-4. block 256.
__global__ __launch_bounds__(256) void mix_kernel(
    const float* __restrict__ Aap, const float* __restrict__ Aue,
    const float* __restrict__ Hm1, const float* __restrict__ Hm2,
    const float* __restrict__ Q1_AP, const float* __restrict__ Q1_UE,
    const float* __restrict__ Q2_AP, const float* __restrict__ Q2_UE,
    const float* __restrict__ P1_AP, const float* __restrict__ P1_UE,
    const float* __restrict__ amAP, const float* __restrict__ amUE,
    float* __restrict__ preAP, float* __restrict__ preUE,
    float* __restrict__ stAP, float* __restrict__ stUE)
{
  __shared__ float qb_s[CH];
  __shared__ float am_s[D1];
  __shared__ float U[CH * 65 + D1 * 64];   // stepA: Qs(65-pad)+As; stepB: Ps(33-pad)+Hs
  const int x = blockIdx.x;
  const int side = (x >= NAP / 64);
  const int tile = side ? x - NAP / 64 : x;
  const int b = blockIdx.y;
  const int N = side ? NUE : NAP;
  const float* Aagg = (side ? Aue : Aap) + (size_t)b * D1 * N + tile * 64;
  const float* Hm   = (side ? Hm2 : Hm1) + (size_t)b * D2 * N + tile * 64;
  const float* Q1   = side ? Q1_UE : Q1_AP;
  const float* Q2   = side ? Q2_UE : Q2_AP;
  const float* P1   = side ? P1_UE : P1_AP;
  const float* amO  = side ? amAP : amUE;        // cross-side mean feeds qb
  const float invO  = side ? (1.0f / NAP) : (1.0f / NUE);
  float* pre        = (side ? preUE : preAP) + (size_t)b * CH * N + tile * 64;
  float* stat       = side ? stUE : stAP;

  const int t = threadIdx.x;
  if (t < D1) am_s[t] = amO[b * D1 + t] * invO;
  __syncthreads();
  if (t < CH) {
    float s = 0.f;
    #pragma unroll
    for (int d = 0; d < D1; ++d) s = fmaf(Q2[t * D1 + d], am_s[d], s);
    qb_s[t] = 2.f * s;
  }

  // step A: Q1 x Aagg
  float* Qs = U;               // CH x 65
  float* As = U + CH * 65;     // D1 x 64
  for (int i = t; i < CH * D1; i += 256) Qs[(i >> 6) * 65 + (i & 63)] = Q1[i];
  for (int i = t; i < D1 * 64; i += 256) As[i] = Aagg[(size_t)(i >> 6) * N + (i & 63)];
  __syncthreads();

  const int tn = t & 15, to = t >> 4;
  float accQ[8][4] = {};
  for (int d = 0; d < D1; ++d) {
    float4 a = *(const float4*)&As[d * 64 + tn * 4];
    #pragma unroll
    for (int oi = 0; oi < 8; ++oi) {
      float w = Qs[(to * 8 + oi) * 65 + d];
      accQ[oi][0] = fmaf(w, a.x, accQ[oi][0]);
      accQ[oi][1] = fmaf(w, a.y, accQ[oi][1]);
      accQ[oi][2] = fmaf(w, a.z, accQ[oi][2]);
      accQ[oi][3] = fmaf(w, a.w, accQ[oi][3]);
    }
  }
  __syncthreads();   // before overwriting U

  // step B: P1 x Hm (reuse U)
  float* Ps = U;               // CH x 33
  float* Hs = U + CH * 33;     // D2 x 64
  for (int i = t; i < CH * D2; i += 256) Ps[(i >> 5) * 33 + (i & 31)] = P1[i];
  for (int i = t; i < D2 * 64; i += 256) Hs[i] = Hm[(size_t)(i >> 6) * N + (i & 63)];
  __syncthreads();

  float accP[8][4] = {};
  for (int c = 0; c < D2; ++c) {
    float4 h = *(const float4*)&Hs[c * 64 + tn * 4];
    #pragma unroll
    for (int oi = 0; oi < 8; ++oi) {
      float w = Ps[(to * 8 + oi) * 33 + c];
      accP[oi][0] = fmaf(w, h.x, accP[oi][0]);
      accP[oi][1] = fmaf(w, h.y, accP[oi][1]);
      accP[oi][2] = fmaf(w, h.z, accP[oi][2]);
      accP[oi][3] = fmaf(w, h.w, accP[oi][3]);
    }
  }

  #pragma unroll
  for (int oi = 0; oi < 8; ++oi) {
    const int o = to * 8 + oi;
    const float base = qb_s[o];
    float4 r;
    r.x = fmaxf(2.f * accQ[oi][0] + base + 0.1f * accP[oi][0], 0.f);
    r.y = fmaxf(2.f * accQ[oi][1] + base + 0.1f * accP[oi][1], 0.f);
    r.z = fmaxf(2.f * accQ[oi][2] + base + 0.1f * accP[oi][2], 0.f);
    r.w = fmaxf(2.f * accQ[oi][3] + base + 0.1f * accP[oi][3], 0.f);
    *(float4*)&pre[(size_t)o * N + tn * 4] = r;
    float s1 = r.x + r.y + r.z + r.w;
    float s2 = r.x * r.x + r.y * r.y + r.z * r.z + r.w * r.w;
    #pragma unroll
    for (int m = 1; m < 16; m <<= 1) { s1 += __shfl_xor(s1, m, 64); s2 += __shfl_xor(s2, m, 64); }
    if (tn == 0) { atomicAdd(&stat[o], s1); atomicAdd(&stat[CH + o], s2); }
  }
}

// ---------------- K3: inline BN scale/shift + normalize + outputs + info_xz ----------------
// grid (6, BB): x<4 -> AP tile x, x>=4 -> UE tile x-4.
__global__ __launch_bounds__(256) void finalize_kernel(
    const float* __restrict__ preAP, const float* __restrict__ preUE,
    const float* __restrict__ stAP, const float* __restrict__ stUE,
    const float* __restrict__ bnw, const float* __restrict__ bnb,
    float* __restrict__ outAP, float* __restrict__ outUE,
    float* __restrict__ IXZAP, float* __restrict__ IXZUE)
{
  const int x = blockIdx.x;
  const int side = (x >= NAP / 64);
  const int tile = side ? x - NAP / 64 : x;
  const int N = side ? NUE : NAP;
  const float* pre  = side ? preUE : preAP;
  const float* stat = side ? stUE : stAP;
  float* outp       = side ? outUE : outAP;
  float* IXZ        = side ? IXZUE : IXZAP;
  const unsigned k0 = side ? SK4.hi : SK3.hi;
  const unsigned k1 = side ? SK4.lo : SK3.lo;
  const int ROWS = BB * N;
  const int t = threadIdx.x;

  __shared__ float ss_s[2 * CH];
  if (t < CH) {
    const float inv = 1.0f / (float)ROWS;
    float m = stat[t] * inv;
    float v = stat[CH + t] * inv - m * m;
    float sc = bnw[t] / sqrtf(v + 1e-5f);
    ss_s[t] = sc; ss_s[CH + t] = bnb[t] - m * sc;
  }
  __syncthreads();

  const int b = blockIdx.y;
  const int lane = t & 63;
  const int og = t >> 6;
  const int n = tile * 64 + lane;
  const int row = b * N + n;
  const float* preb = pre + (size_t)b * CH * N;

  float accZ = 0.f, sumlog = 0.f;
  for (int oi = 0; oi < 16; ++oi) {
    const int o = og * 16 + oi;
    float mpre = preb[o * N + n];
    float rraw = preb[(o + 64) * N + n];
    float x0 = fmaf(mpre, ss_s[o], ss_s[CH + o]);
    float x1 = fmaf(rraw, ss_s[o + 64], ss_s[CH + o + 64]);
    outp[((size_t)b * OUTC + o) * N + n] = x0;
    float stdv = softplus_f(x1) + 1e-10f;
    sumlog += logf(stdv);
    #pragma unroll
    for (int s = 0; s < SS; ++s) {
      unsigned idx = (unsigned)((s * ROWS + row) * 64 + o);
      float eps = normal_from_bits(rb32(k0, k1, idx));
      float Z = fmaf(stdv, eps, x0);
      accZ += 0.5f * (Z * Z - eps * eps);
    }
  }
  __shared__ float pz[4][64];
  __shared__ float pl[4][64];
  pz[og][lane] = accZ; pl[og][lane] = sumlog;
  __syncthreads();
  if (og == 0) {
    float az = pz[0][lane] + pz[1][lane] + pz[2][lane] + pz[3][lane];
    float al = pl[0][lane] + pl[1][lane] + pl[2][lane] + pl[3][lane];
    float rv = az * (1.0f / SS) - al;
    #pragma unroll
    for (int m = 32; m; m >>= 1) rv += __shfl_xor(rv, m, 64);
    if (lane == 0) atomicAdd(&IXZ[b], rv);
  }
}

// ---------------- workspace layout (floats) ----------------
constexpr size_t OFF_AMEAN_AP = 0;
constexpr size_t OFF_AMEAN_UE = OFF_AMEAN_AP + BB * D1;
constexpr size_t OFF_STAT_AP  = OFF_AMEAN_UE + BB * D1;
constexpr size_t OFF_STAT_UE  = OFF_STAT_AP + 2 * CH;
constexpr size_t OFF_AAP      = OFF_STAT_UE + 2 * CH;
constexpr size_t OFF_AUE      = OFF_AAP + (size_t)BB * D1 * NAP;
constexpr size_t OFF_HM1      = OFF_AUE + (size_t)BB * D1 * NUE;
constexpr size_t OFF_HM2      = OFF_HM1 + (size_t)BB * D2 * NAP;
constexpr size_t OFF_PRE_AP   = OFF_HM2 + (size_t)BB * D2 * NUE;
constexpr size_t OFF_PRE_UE   = OFF_PRE_AP + (size_t)BB * CH * NAP;
constexpr size_t WS_FLOATS    = OFF_PRE_UE + (size_t)BB * CH * NUE;

extern "C" void kernel_launch(void* const* d_in, const int* in_sizes, int n_in,
                              void* d_out, int out_size, void* d_ws, size_t ws_size,
                              hipStream_t stream)
{
  const float* A_AP  = (const float*)d_in[0];
  const float* A_UE  = (const float*)d_in[1];
  const float* H     = (const float*)d_in[2];
  const float* Q1_AP = (const float*)d_in[3];
  const float* Q2_AP = (const float*)d_in[4];
  const float* Q1_UE = (const float*)d_in[5];
  const float* Q2_UE = (const float*)d_in[6];
  const float* P1_AP = (const float*)d_in[7];
  const float* P1_UE = (const float*)d_in[8];
  const float* AttAP = (const float*)d_in[9];
  const float* AttUE = (const float*)d_in[10];
  const float* bnw   = (const float*)d_in[11];
  const float* bnb   = (const float*)d_in[12];
  const int* GraphAP = (const int*)d_in[13];
  const int* GraphUE = (const int*)d_in[14];
  const int* GFA_AP  = (const int*)d_in[15];
  const int* GFA_UE  = (const int*)d_in[16];

  float* ws = (float*)d_ws;
  if (ws_size < WS_FLOATS * sizeof(float)) return;

  float* amAP  = ws + OFF_AMEAN_AP;
  float* amUE  = ws + OFF_AMEAN_UE;
  float* stAP  = ws + OFF_STAT_AP;
  float* stUE  = ws + OFF_STAT_UE;
  float* Aap   = ws + OFF_AAP;
  float* Aue   = ws + OFF_AUE;
  float* Hm1   = ws + OFF_HM1;
  float* Hm2   = ws + OFF_HM2;
  float* preAP = ws + OFF_PRE_AP;
  float* preUE = ws + OFF_PRE_UE;

  float* out     = (float*)d_out;
  float* outAP   = out;
  float* outUE   = out + (size_t)BB * OUTC * NAP;
  float* IXZ_AP  = out + (size_t)BB * OUTC * (NAP + NUE);
  float* IXZ_UE  = IXZ_AP + BB;
  float* IAZ_AP  = IXZ_UE + BB;
  float* IAZ_UE  = IAZ_AP + BB;

  // K1: edge gates + KL + aggregation (128 blocks) || H means (2048 blocks)
  k1_kernel<<<dim3(NEB + BB * D2), 256, 0, stream>>>(
      A_AP, A_UE, H, GraphAP, GraphUE, AttAP, AttUE, GFA_AP, GFA_UE,
      Aap, Aue, amAP, amUE, Hm1, Hm2, IAZ_AP, IAZ_UE, stAP, IXZ_AP);

  // K2: qb inline + einsums + relu + BN stats
  mix_kernel<<<dim3(NAP / 64 + NUE / 64, BB), 256, 0, stream>>>(
      Aap, Aue, Hm1, Hm2, Q1_AP, Q1_UE, Q2_AP, Q2_UE, P1_AP, P1_UE,
      amAP, amUE, preAP, preUE, stAP, stUE);

  // K3: BN inline + normalize + outputs + info_xz
  finalize_kernel<<<dim3(NAP / 64 + NUE / 64, BB), 256, 0, stream>>>(
      preAP, preUE, stAP, stUE, bnw, bnb, outAP, outUE, IXZ_AP, IXZ_UE);
}